// Round 2
// baseline (6602.772 us; speedup 1.0000x reference)
//
#include <hip/hip_runtime.h>
#include <cstdint>
#include <cstddef>

#define NN   10000
#define EE   40000
#define DIN_ 11
#define DD   64
#define LL   4
#define BB   512
#define MM   3
#define K1   128   // 2*D
#define DD2  4096  // D*D

typedef unsigned short ushort_t;
typedef unsigned int   uint_t;

__device__ __forceinline__ float bfu(ushort_t u) {
  return __uint_as_float(((uint_t)u) << 16);
}
__device__ __forceinline__ float bflo(uint_t u) { return __uint_as_float(u << 16); }
__device__ __forceinline__ float bfhi(uint_t u) { return __uint_as_float(u & 0xffff0000u); }
__device__ __forceinline__ ushort_t f2bf(float f) {
  uint_t u = __float_as_uint(f);
  u = (u + 0x7fffu + ((u >> 16) & 1u)) >> 16;
  return (ushort_t)u;
}
__device__ __forceinline__ float sigmf_(float x) { return 1.f / (1.f + expf(-x)); }
__device__ __forceinline__ float siluf_(float x) { return x / (1.f + expf(-x)); }

// ---------------- dtype detect: edge_attr is uniform[0,1) ----------------
// If bf16: every ushort has sign=0 and value <= 0x3F80 (1.0).
// If fp32: half the ushorts are random mantissa words -> fails w.p. ~1.
__global__ void k_detect(const ushort_t* __restrict__ ea, int* __restrict__ flag) {
  __shared__ int bad;
  if (threadIdx.x == 0) bad = 0;
  __syncthreads();
  ushort_t u = ea[threadIdx.x];  // first 256 ushorts (in-bounds either way)
  if ((u & 0x8000u) || u > 0x3F80u) atomicAdd(&bad, 1);
  __syncthreads();
  if (threadIdx.x == 0) *flag = (bad == 0) ? 1 : 0;
}

// ---------------- canonicalize float inputs to fp32 in ws ----------------
#define NCANON 16
struct CanonArgs {
  const void* src[NCANON];
  float* dst[NCANON];
  int n[NCANON];
};
__global__ void k_canon(CanonArgs a, const int* __restrict__ flag) {
  const int ai = blockIdx.y;
  const int n = a.n[ai];
  const int i = blockIdx.x * 256 + threadIdx.x;
  if (i >= n) return;
  float v;
  if (*flag) v = bfu(((const ushort_t*)a.src[ai])[i]);
  else       v = ((const float*)a.src[ai])[i];
  a.dst[ai][i] = v;
}

// Wn2 canonical form: packed bf16 pairs (uint per 2 elements), row-major [K1][DD2]
__global__ void k_wn2(const void* __restrict__ Wn2, uint_t* __restrict__ pk,
                      const int* __restrict__ flag) {
  const int i = blockIdx.x * 256 + threadIdx.x;
  if (i >= K1 * DD2 / 2) return;
  if (*flag) {
    pk[i] = ((const uint_t*)Wn2)[i];
  } else {
    const float* f = (const float*)Wn2;
    uint_t lo = f2bf(f[2 * i]);
    uint_t hi = f2bf(f[2 * i + 1]);
    pk[i] = lo | (hi << 16);
  }
}

// ---------------- node embed: h = x @ W0 + b0 ----------------
__global__ void k_embed(const float* __restrict__ x, const float* __restrict__ W0,
                        const float* __restrict__ b0, float* __restrict__ h) {
  int idx = blockIdx.x * 256 + threadIdx.x;
  if (idx >= NN * DD) return;
  int n = idx >> 6, d = idx & 63;
  float acc = b0[d];
  for (int i = 0; i < DIN_; ++i)
    acc += x[n * DIN_ + i] * W0[i * DD + d];
  h[idx] = acc;
}

// ---------------- edge MLP layer1: hn1 = silu(ea @ Wn1 + bn1), packed bf16 ----------------
__global__ void k_edgemlp(const float* __restrict__ ea, const float* __restrict__ Wn1,
                          const float* __restrict__ bn1, uint_t* __restrict__ hn1pk) {
  int idx = blockIdx.x * 256 + threadIdx.x;  // pair index: e*64 + j
  if (idx >= EE * (K1 / 2)) return;
  int e = idx >> 6, j = idx & 63;
  int k0 = 2 * j, k1 = 2 * j + 1;
  float a0 = ea[e * 4 + 0], a1 = ea[e * 4 + 1], a2 = ea[e * 4 + 2], a3 = ea[e * 4 + 3];
  float t0 = bn1[k0] + a0 * Wn1[k0] + a1 * Wn1[K1 + k0] + a2 * Wn1[2 * K1 + k0] + a3 * Wn1[3 * K1 + k0];
  float t1 = bn1[k1] + a0 * Wn1[k1] + a1 * Wn1[K1 + k1] + a2 * Wn1[2 * K1 + k1] + a3 * Wn1[3 * K1 + k1];
  uint_t lo = f2bf(siluf_(t0));
  uint_t hi = f2bf(siluf_(t1));
  hn1pk[idx] = lo | (hi << 16);
}

// ---------------- CSR build ----------------
__global__ void k_hist(const int* __restrict__ ei, int* __restrict__ cnt_s, int* __restrict__ cnt_d) {
  int e = blockIdx.x * 256 + threadIdx.x;
  if (e >= EE) return;
  atomicAdd(&cnt_s[ei[e]], 1);
  atomicAdd(&cnt_d[ei[EE + e]], 1);
}

__global__ void k_scan(const int* __restrict__ cnt0, int* __restrict__ rp0,
                       const int* __restrict__ cnt1, int* __restrict__ rp1) {
  const int* cnt = blockIdx.x ? cnt1 : cnt0;
  int* rp = blockIdx.x ? rp1 : rp0;
  __shared__ int part[1024];
  const int tid = threadIdx.x;
  const int chunk = (NN + 1023) / 1024;
  int s = 0;
  for (int j = 0; j < chunk; ++j) {
    int idx = tid * chunk + j;
    if (idx < NN) s += cnt[idx];
  }
  part[tid] = s;
  __syncthreads();
  for (int off = 1; off < 1024; off <<= 1) {
    int v = (tid >= off) ? part[tid - off] : 0;
    __syncthreads();
    part[tid] += v;
    __syncthreads();
  }
  int base = (tid == 0) ? 0 : part[tid - 1];
  for (int j = 0; j < chunk; ++j) {
    int idx = tid * chunk + j;
    if (idx < NN) { rp[idx] = base; base += cnt[idx]; }
  }
  if (tid == 1023) rp[NN] = part[1023];
}

__global__ void k_fill(const int* __restrict__ ei,
                       const int* __restrict__ rps, int* __restrict__ cur_s, int* __restrict__ eds,
                       const int* __restrict__ rpd, int* __restrict__ cur_d, int* __restrict__ edd) {
  int e = blockIdx.x * 256 + threadIdx.x;
  if (e >= EE) return;
  int s = ei[e], d = ei[EE + e];
  int ps = atomicAdd(&cur_s[s], 1);
  eds[rps[s] + ps] = e;
  int pd = atomicAdd(&cur_d[d], 1);
  edd[rpd[d] + pd] = e;
}

// graph segment offsets from sorted batch
__global__ void k_goff(const int* __restrict__ batch, int* __restrict__ goff) {
  int g = blockIdx.x * 256 + threadIdx.x;
  if (g > BB) return;
  int lo = 0, hi = NN;
  while (lo < hi) {
    int mid = (lo + hi) >> 1;
    if (batch[mid] < g) lo = mid + 1; else hi = mid;
  }
  goff[g] = lo;
}

// ---------------- fused NNConv message kernel ----------------
// Per block: 2 src nodes. Phase 1: G[n,k,f] = sum_d h[n,d]*Wn2[k,d*64+f] into LDS.
// Phase 2: for each out-edge e of n: msg[e,f] = sum_k hn1[e,k]*G[n,k,f] + sum_d h[n,d]*bn2[d*64+f]
__global__ __launch_bounds__(256, 2) void k_conv(
    const float* __restrict__ h, const uint_t* __restrict__ hn1pk,
    const uint_t* __restrict__ Wn2pk, const float* __restrict__ bn2,
    const int* __restrict__ rps, const int* __restrict__ eds,
    float* __restrict__ msg) {
  __shared__ float G[2][K1][DD];  // 64 KB
  const int tid = threadIdx.x;
  const int n0 = blockIdx.x * 2;

  float hr0[DD], hr1[DD];
  {
    const float4* p0 = (const float4*)(h + (size_t)n0 * DD);
    const float4* p1 = (const float4*)(h + (size_t)(n0 + 1) * DD);
#pragma unroll
    for (int i = 0; i < DD / 4; ++i) {
      float4 a = p0[i]; float4 b = p1[i];
      hr0[4 * i] = a.x; hr0[4 * i + 1] = a.y; hr0[4 * i + 2] = a.z; hr0[4 * i + 3] = a.w;
      hr1[4 * i] = b.x; hr1[4 * i + 1] = b.y; hr1[4 * i + 2] = b.z; hr1[4 * i + 3] = b.w;
    }
  }

  const int f2 = tid & 31;   // bf16-pair column (covers f = 2*f2, 2*f2+1)
  const int k0 = tid >> 5;   // 0..7
  for (int kk = 0; kk < K1; kk += 8) {
    const int k = kk + k0;
    const uint_t* wp = Wn2pk + (size_t)k * (DD2 / 2) + f2;
    float a00 = 0.f, a01 = 0.f, a10 = 0.f, a11 = 0.f;
#pragma unroll
    for (int d = 0; d < DD; ++d) {
      uint_t u = wp[(size_t)d * 32];
      float wlo = bflo(u), whi = bfhi(u);
      a00 += hr0[d] * wlo; a01 += hr0[d] * whi;
      a10 += hr1[d] * wlo; a11 += hr1[d] * whi;
    }
    G[0][k][2 * f2] = a00; G[0][k][2 * f2 + 1] = a01;
    G[1][k][2 * f2] = a10; G[1][k][2 * f2 + 1] = a11;
  }
  __syncthreads();

  const int wave = tid >> 6, lane = tid & 63;
  const int t = wave >> 1;
  const int n = n0 + t;
  float bias = 0.f;
#pragma unroll
  for (int d = 0; d < DD; ++d)
    bias += h[(size_t)n * DD + d] * bn2[d * DD + lane];
  const int e1 = rps[n + 1];
  for (int ii = rps[n] + (wave & 1); ii < e1; ii += 2) {
    const int e = eds[ii];
    const uint4* hp = (const uint4*)(hn1pk + (size_t)e * (K1 / 2));
    float m = bias;
#pragma unroll
    for (int j4 = 0; j4 < K1 / 8; ++j4) {
      uint4 v = hp[j4];
      const int kb = 8 * j4;
      m += bflo(v.x) * G[t][kb + 0][lane] + bfhi(v.x) * G[t][kb + 1][lane]
         + bflo(v.y) * G[t][kb + 2][lane] + bfhi(v.y) * G[t][kb + 3][lane]
         + bflo(v.z) * G[t][kb + 4][lane] + bfhi(v.z) * G[t][kb + 5][lane]
         + bflo(v.w) * G[t][kb + 6][lane] + bfhi(v.w) * G[t][kb + 7][lane];
    }
    msg[(size_t)e * DD + lane] = m;
  }
}

// ---------------- aggregate (dst-CSR) + root GEMM + residual, in place ----------------
__global__ void k_update(float* __restrict__ h, const float* __restrict__ msg,
                         const int* __restrict__ rpd, const int* __restrict__ edd,
                         const float* __restrict__ root, const float* __restrict__ cb,
                         int l) {
  __shared__ float hl[DD];
  const int n = blockIdx.x, f = threadIdx.x;
  hl[f] = h[(size_t)n * DD + f];
  __syncthreads();
  float s = 0.f;
  const int i1 = rpd[n + 1];
  for (int ii = rpd[n]; ii < i1; ++ii)
    s += msg[(size_t)edd[ii] * DD + f];
  float acc = hl[f] + s + cb[l * DD + f];
  const float* rp = root + (size_t)l * DD2 + f;
#pragma unroll
  for (int d = 0; d < DD; ++d) acc += hl[d] * rp[d * DD];
  h[(size_t)n * DD + f] = acc;
}

// ---------------- Set2Set LSTM step ----------------
__global__ void k_lstm(const float* __restrict__ qstar, float* __restrict__ hs, float* __restrict__ cs,
                       const float* __restrict__ Wih, const float* __restrict__ Whh,
                       const float* __restrict__ lb) {
  __shared__ float qs[K1];
  __shared__ float hsl[DD];
  const int b = blockIdx.x, d = threadIdx.x;
  hsl[d] = hs[(size_t)b * DD + d];
  qs[d] = qstar[(size_t)b * K1 + d];
  qs[DD + d] = qstar[(size_t)b * K1 + DD + d];
  __syncthreads();
  float g4[4];
  for (int gi = 0; gi < 4; ++gi) {
    const int j = gi * DD + d;
    float a = lb[j];
    const float* wi = Wih + (size_t)j * K1;
    const float* wh = Whh + (size_t)j * DD;
    for (int i = 0; i < K1; ++i) a += qs[i] * wi[i];
    for (int i = 0; i < DD; ++i) a += hsl[i] * wh[i];
    g4[gi] = a;
  }
  float ig = sigmf_(g4[0]), fg = sigmf_(g4[1]), gg = tanhf(g4[2]), og = sigmf_(g4[3]);
  float c = fg * cs[(size_t)b * DD + d] + ig * gg;
  cs[(size_t)b * DD + d] = c;
  hs[(size_t)b * DD + d] = og * tanhf(c);
}

// ---------------- Set2Set attention + readout, one block per graph ----------------
#define EVCAP 2048
__global__ void k_attn(const float* __restrict__ h, const float* __restrict__ hs,
                       const int* __restrict__ goff, float* __restrict__ qstar) {
  __shared__ float q[DD];
  __shared__ float red[256];
  __shared__ float ev[EVCAP];
  __shared__ float rp[4][DD];
  const int g = blockIdx.x, tid = threadIdx.x;
  if (tid < DD) q[tid] = hs[(size_t)g * DD + tid];
  __syncthreads();
  const int i0 = goff[g];
  int cnt = goff[g + 1] - i0;
  if (cnt > EVCAP) cnt = EVCAP;  // never triggers for this data
  float lmax = -1e30f;
  for (int j = tid; j < cnt; j += 256) {
    const float* hp = h + (size_t)(i0 + j) * DD;
    float e = 0.f;
#pragma unroll
    for (int d = 0; d < DD; ++d) e += hp[d] * q[d];
    ev[j] = e;
    lmax = fmaxf(lmax, e);
  }
  red[tid] = lmax;
  __syncthreads();
  for (int s = 128; s > 0; s >>= 1) {
    if (tid < s) red[tid] = fmaxf(red[tid], red[tid + s]);
    __syncthreads();
  }
  const float emax = red[0];
  __syncthreads();
  float lsum = 0.f;
  for (int j = tid; j < cnt; j += 256) {
    float ex = expf(ev[j] - emax);
    ev[j] = ex;
    lsum += ex;
  }
  red[tid] = lsum;
  __syncthreads();
  for (int s = 128; s > 0; s >>= 1) {
    if (tid < s) red[tid] += red[tid + s];
    __syncthreads();
  }
  const float denom = red[0];
  const int f = tid & 63, grp = tid >> 6;
  float acc = 0.f;
  for (int j = grp; j < cnt; j += 4)
    acc += ev[j] * h[(size_t)(i0 + j) * DD + f];
  rp[grp][f] = acc;
  __syncthreads();
  if (tid < DD) {
    float r = rp[0][tid] + rp[1][tid] + rp[2][tid] + rp[3][tid];
    r = (cnt > 0 && denom > 0.f) ? r / denom : 0.f;
    qstar[(size_t)g * K1 + DD + tid] = r;
    qstar[(size_t)g * K1 + tid] = q[tid];
  }
}

// ---------------- output MLP ----------------
__global__ void k_out(const float* __restrict__ qstar,
                      const float* __restrict__ Wo1, const float* __restrict__ bo1,
                      const float* __restrict__ Wo2, const float* __restrict__ bo2,
                      void* __restrict__ outv, const int* __restrict__ flag) {
  __shared__ float qs[K1];
  const int b = blockIdx.x, d = threadIdx.x;
  qs[d] = qstar[(size_t)b * K1 + d];
  qs[DD + d] = qstar[(size_t)b * K1 + DD + d];
  __syncthreads();
  float t = bo1[d];
  for (int i = 0; i < K1; ++i) t += qs[i] * Wo1[i * DD + d];
  float s = siluf_(t) * Wo2[d];
  for (int off = 32; off > 0; off >>= 1) s += __shfl_down(s, off);
  if (d == 0) {
    float v = s + bo2[0];
    if (*flag) ((ushort_t*)outv)[b] = f2bf(v);
    else       ((float*)outv)[b] = v;
  }
}

extern "C" void kernel_launch(void* const* d_in, const int* in_sizes, int n_in,
                              void* d_out, int out_size, void* d_ws, size_t ws_size,
                              hipStream_t stream) {
  const void* x_r    = d_in[0];
  const int*  ei     = (const int*)d_in[1];
  const void* ea_r   = d_in[2];
  const int*  batch  = (const int*)d_in[3];
  const void* W0_r   = d_in[4];
  const void* b0_r   = d_in[5];
  const void* Wn1_r  = d_in[6];
  const void* bn1_r  = d_in[7];
  const void* Wn2_r  = d_in[8];
  const void* bn2_r  = d_in[9];
  const void* root_r = d_in[10];
  const void* cb_r   = d_in[11];
  const void* Wih_r  = d_in[12];
  const void* Whh_r  = d_in[13];
  const void* lb_r   = d_in[14];
  const void* Wo1_r  = d_in[15];
  const void* bo1_r  = d_in[16];
  const void* Wo2_r  = d_in[17];
  const void* bo2_r  = d_in[18];

  char* w = (char*)d_ws;
  size_t off = 0;
  auto alloc = [&](size_t bytes) -> void* {
    void* p = w + off;
    off = (off + bytes + 255) & ~(size_t)255;
    return p;
  };
  int* flag = (int*)alloc(4);
  // canonical fp32 inputs
  float* xc    = (float*)alloc((size_t)NN * DIN_ * 4);
  float* eac   = (float*)alloc((size_t)EE * 4 * 4);
  float* W0c   = (float*)alloc((size_t)DIN_ * DD * 4);
  float* b0c   = (float*)alloc((size_t)DD * 4);
  float* Wn1c  = (float*)alloc((size_t)4 * K1 * 4);
  float* bn1c  = (float*)alloc((size_t)K1 * 4);
  float* bn2c  = (float*)alloc((size_t)DD2 * 4);
  float* rootc = (float*)alloc((size_t)LL * DD2 * 4);
  float* cbc   = (float*)alloc((size_t)LL * DD * 4);
  float* Wihc  = (float*)alloc((size_t)4 * DD * K1 * 4);
  float* Whhc  = (float*)alloc((size_t)4 * DD * DD * 4);
  float* lbc   = (float*)alloc((size_t)4 * DD * 4);
  float* Wo1c  = (float*)alloc((size_t)K1 * DD * 4);
  float* bo1c  = (float*)alloc((size_t)DD * 4);
  float* Wo2c  = (float*)alloc((size_t)DD * 4);
  float* bo2c  = (float*)alloc((size_t)4);
  uint_t* Wn2pk = (uint_t*)alloc((size_t)K1 * DD2 / 2 * 4);  // 1 MB
  float* h     = (float*)alloc((size_t)NN * DD * 4);          // 2.56 MB
  uint_t* hn1pk= (uint_t*)alloc((size_t)EE * (K1 / 2) * 4);   // 10.24 MB
  float* msg   = (float*)alloc((size_t)EE * DD * 4);          // 10.24 MB
  int* cnts  = (int*)alloc((size_t)4 * NN * 4);
  int* rps   = (int*)alloc((size_t)(NN + 1) * 4);
  int* rpd   = (int*)alloc((size_t)(NN + 1) * 4);
  int* eds   = (int*)alloc((size_t)EE * 4);
  int* edd   = (int*)alloc((size_t)EE * 4);
  int* goff  = (int*)alloc((size_t)(BB + 1) * 4);
  float* s2s = (float*)alloc((size_t)BB * 256 * 4);
  float* qstar = s2s;
  float* hs = s2s + (size_t)BB * K1;
  float* cs = hs + (size_t)BB * DD;

  int* cnt_s = cnts;
  int* cur_s = cnts + NN;
  int* cnt_d = cnts + 2 * NN;
  int* cur_d = cnts + 3 * NN;

  hipMemsetAsync(cnts, 0, (size_t)4 * NN * 4, stream);
  hipMemsetAsync(s2s, 0, (size_t)BB * 256 * 4, stream);

  k_detect<<<1, 256, 0, stream>>>((const ushort_t*)ea_r, flag);

  CanonArgs ca;
  const void* srcs[NCANON] = {x_r, ea_r, W0_r, b0_r, Wn1_r, bn1_r, bn2_r, root_r,
                              cb_r, Wih_r, Whh_r, lb_r, Wo1_r, bo1_r, Wo2_r, bo2_r};
  float* dsts[NCANON] = {xc, eac, W0c, b0c, Wn1c, bn1c, bn2c, rootc,
                         cbc, Wihc, Whhc, lbc, Wo1c, bo1c, Wo2c, bo2c};
  int cnts_c[NCANON] = {NN * DIN_, EE * 4, DIN_ * DD, DD, 4 * K1, K1, DD2, LL * DD2,
                        LL * DD, 4 * DD * K1, 4 * DD * DD, 4 * DD, K1 * DD, DD, DD, 1};
  for (int i = 0; i < NCANON; ++i) { ca.src[i] = srcs[i]; ca.dst[i] = dsts[i]; ca.n[i] = cnts_c[i]; }
  {
    dim3 grid((EE * 4 + 255) / 256, NCANON);
    k_canon<<<grid, 256, 0, stream>>>(ca, flag);
  }
  k_wn2<<<(K1 * DD2 / 2 + 255) / 256, 256, 0, stream>>>(Wn2_r, Wn2pk, flag);

  k_embed<<<(NN * DD + 255) / 256, 256, 0, stream>>>(xc, W0c, b0c, h);
  k_edgemlp<<<(EE * (K1 / 2) + 255) / 256, 256, 0, stream>>>(eac, Wn1c, bn1c, hn1pk);
  k_hist<<<(EE + 255) / 256, 256, 0, stream>>>(ei, cnt_s, cnt_d);
  k_scan<<<2, 1024, 0, stream>>>(cnt_s, rps, cnt_d, rpd);
  k_fill<<<(EE + 255) / 256, 256, 0, stream>>>(ei, rps, cur_s, eds, rpd, cur_d, edd);
  k_goff<<<(BB + 1 + 255) / 256, 256, 0, stream>>>(batch, goff);

  for (int l = 0; l < LL; ++l) {
    k_conv<<<NN / 2, 256, 0, stream>>>(h, hn1pk, Wn2pk, bn2c, rps, eds, msg);
    k_update<<<NN, DD, 0, stream>>>(h, msg, rpd, edd, rootc, cbc, l);
  }

  for (int m = 0; m < MM; ++m) {
    k_lstm<<<BB, DD, 0, stream>>>(qstar, hs, cs, Wihc, Whhc, lbc);
    k_attn<<<BB, 256, 0, stream>>>(h, hs, goff, qstar);
  }
  k_out<<<BB, DD, 0, stream>>>(qstar, Wo1c, bo1c, Wo2c, bo2c, d_out, flag);
}

// Round 3
// 2693.140 us; speedup vs baseline: 2.4517x; 2.4517x over previous
//
#include <hip/hip_runtime.h>
#include <cstdint>
#include <cstddef>

#define NN   10000
#define EE   40000
#define DIN_ 11
#define DD   64
#define LL   4
#define BB   512
#define MM   3
#define K1   128   // 2*D
#define DD2  4096  // D*D

typedef unsigned short ushort_t;
typedef unsigned int   uint_t;

__device__ __forceinline__ float bfu(ushort_t u) { return __uint_as_float(((uint_t)u) << 16); }
__device__ __forceinline__ float bflo(uint_t u) { return __uint_as_float(u << 16); }
__device__ __forceinline__ float bfhi(uint_t u) { return __uint_as_float(u & 0xffff0000u); }
__device__ __forceinline__ ushort_t f2bf(float f) {
  uint_t u = __float_as_uint(f);
  u = (u + 0x7fffu + ((u >> 16) & 1u)) >> 16;
  return (ushort_t)u;
}
__device__ __forceinline__ float sigmf_(float x) { return 1.f / (1.f + expf(-x)); }
__device__ __forceinline__ float siluf_(float x) { return x / (1.f + expf(-x)); }

// packed-bf16 pair dot product with fp32 accumulate
#if defined(__HIP_DEVICE_COMPILE__) && __has_builtin(__builtin_amdgcn_fdot2_f32_bf16)
typedef __bf16 bf16x2_t __attribute__((ext_vector_type(2)));
__device__ __forceinline__ float dot2a(uint_t a, uint_t b, float c) {
  union { uint_t u; bf16x2_t v; } ua, ub;
  ua.u = a; ub.u = b;
  return __builtin_amdgcn_fdot2_f32_bf16(ua.v, ub.v, c, false);
}
#else
__device__ __forceinline__ float dot2a(uint_t a, uint_t b, float c) {
  return c + bflo(a) * bflo(b) + bfhi(a) * bfhi(b);
}
#endif

// ---------------- dtype detect: edge_attr is uniform[0,1) ----------------
__global__ void k_detect(const ushort_t* __restrict__ ea, int* __restrict__ flag) {
  __shared__ int bad;
  if (threadIdx.x == 0) bad = 0;
  __syncthreads();
  ushort_t u = ea[threadIdx.x];
  if ((u & 0x8000u) || u > 0x3F80u) atomicAdd(&bad, 1);
  __syncthreads();
  if (threadIdx.x == 0) *flag = (bad == 0) ? 1 : 0;
}

// ---------------- canonicalize float inputs to fp32 in ws ----------------
#define NCANON 16
struct CanonArgs {
  const void* src[NCANON];
  float* dst[NCANON];
  int n[NCANON];
};
__global__ void k_canon(CanonArgs a, const int* __restrict__ flag) {
  const int ai = blockIdx.y;
  const int n = a.n[ai];
  const int i = blockIdx.x * 256 + threadIdx.x;
  if (i >= n) return;
  float v;
  if (*flag) v = bfu(((const ushort_t*)a.src[ai])[i]);
  else       v = ((const float*)a.src[ai])[i];
  a.dst[ai][i] = v;
}

// ---------------- Wn2 repack: Wn2r[k][f][dp] = pair(Wn2[k][2dp*64+f], Wn2[k][(2dp+1)*64+f]) ----------------
__global__ void k_wn2r(const void* __restrict__ Wn2, uint_t* __restrict__ out,
                       const int* __restrict__ flag) {
  const int k = blockIdx.x;      // 128 blocks
  const int tid = threadIdx.x;   // 256
  if (*flag) {
    __shared__ ushort_t row[DD2];  // 8 KB
    const uint4* src = (const uint4*)((const ushort_t*)Wn2 + (size_t)k * DD2);
    ((uint4*)row)[tid] = src[tid];
    ((uint4*)row)[tid + 256] = src[tid + 256];
    __syncthreads();
    for (int j = 0; j < 8; ++j) {
      int o = tid + 256 * j;                 // o = f*32 + dp
      int dp = o & 31, ff = o >> 5;
      uint_t lo = row[(2 * dp) * 64 + ff], hi = row[(2 * dp + 1) * 64 + ff];
      out[(size_t)k * 2048 + o] = lo | (hi << 16);
    }
  } else {
    const float* src = (const float*)Wn2 + (size_t)k * DD2;
    for (int j = 0; j < 8; ++j) {
      int o = tid + 256 * j;
      int dp = o & 31, ff = o >> 5;
      out[(size_t)k * 2048 + o] =
          (uint_t)f2bf(src[(2 * dp) * 64 + ff]) | ((uint_t)f2bf(src[(2 * dp + 1) * 64 + ff]) << 16);
    }
  }
}

// ---------------- bn2 repack: bn2r[f][dp] from fp32 canonical bn2 ----------------
__global__ void k_bn2r(const float* __restrict__ bn2c, uint_t* __restrict__ out) {
  int o = blockIdx.x * 256 + threadIdx.x;   // 2048
  if (o >= 64 * 32) return;
  int dp = o & 31, ff = o >> 5;
  out[o] = (uint_t)f2bf(bn2c[(2 * dp) * 64 + ff]) | ((uint_t)f2bf(bn2c[(2 * dp + 1) * 64 + ff]) << 16);
}

// ---------------- node embed: h (fp32) + hpk (packed bf16) ----------------
__global__ void k_embed(const float* __restrict__ x, const float* __restrict__ W0,
                        const float* __restrict__ b0, float* __restrict__ h,
                        uint_t* __restrict__ hpk) {
  int idx = blockIdx.x * 256 + threadIdx.x;   // NN*32 pair slots
  if (idx >= NN * 32) return;
  int n = idx >> 5, dp = idx & 31;
  int d0 = 2 * dp, d1 = d0 + 1;
  float a0 = b0[d0], a1 = b0[d1];
  for (int i = 0; i < DIN_; ++i) {
    float xv = x[n * DIN_ + i];
    a0 += xv * W0[i * DD + d0];
    a1 += xv * W0[i * DD + d1];
  }
  h[n * DD + d0] = a0;
  h[n * DD + d1] = a1;
  hpk[idx] = (uint_t)f2bf(a0) | ((uint_t)f2bf(a1) << 16);
}

// ---------------- edge MLP layer1: hn1 = silu(ea @ Wn1 + bn1), packed bf16 ----------------
__global__ void k_edgemlp(const float* __restrict__ ea, const float* __restrict__ Wn1,
                          const float* __restrict__ bn1, uint_t* __restrict__ hn1pk) {
  int idx = blockIdx.x * 256 + threadIdx.x;  // e*64 + j
  if (idx >= EE * (K1 / 2)) return;
  int e = idx >> 6, j = idx & 63;
  int k0 = 2 * j, k1 = 2 * j + 1;
  float a0 = ea[e * 4 + 0], a1 = ea[e * 4 + 1], a2 = ea[e * 4 + 2], a3 = ea[e * 4 + 3];
  float t0 = bn1[k0] + a0 * Wn1[k0] + a1 * Wn1[K1 + k0] + a2 * Wn1[2 * K1 + k0] + a3 * Wn1[3 * K1 + k0];
  float t1 = bn1[k1] + a0 * Wn1[k1] + a1 * Wn1[K1 + k1] + a2 * Wn1[2 * K1 + k1] + a3 * Wn1[3 * K1 + k1];
  hn1pk[idx] = (uint_t)f2bf(siluf_(t0)) | ((uint_t)f2bf(siluf_(t1)) << 16);
}

// ---------------- src-CSR build ----------------
__global__ void k_hist(const int* __restrict__ ei, int* __restrict__ cnt_s) {
  int e = blockIdx.x * 256 + threadIdx.x;
  if (e >= EE) return;
  atomicAdd(&cnt_s[ei[e]], 1);
}

__global__ void k_scan(const int* __restrict__ cnt, int* __restrict__ rp) {
  __shared__ int part[1024];
  const int tid = threadIdx.x;
  const int chunk = (NN + 1023) / 1024;
  int s = 0;
  for (int j = 0; j < chunk; ++j) {
    int idx = tid * chunk + j;
    if (idx < NN) s += cnt[idx];
  }
  part[tid] = s;
  __syncthreads();
  for (int off = 1; off < 1024; off <<= 1) {
    int v = (tid >= off) ? part[tid - off] : 0;
    __syncthreads();
    part[tid] += v;
    __syncthreads();
  }
  int base = (tid == 0) ? 0 : part[tid - 1];
  for (int j = 0; j < chunk; ++j) {
    int idx = tid * chunk + j;
    if (idx < NN) { rp[idx] = base; base += cnt[idx]; }
  }
  if (tid == 1023) rp[NN] = part[1023];
}

__global__ void k_fill(const int* __restrict__ ei, const int* __restrict__ rps,
                       int* __restrict__ cur_s, int* __restrict__ eds) {
  int e = blockIdx.x * 256 + threadIdx.x;
  if (e >= EE) return;
  int s = ei[e];
  int ps = atomicAdd(&cur_s[s], 1);
  eds[rps[s] + ps] = e;
}

// graph segment offsets from sorted batch
__global__ void k_goff(const int* __restrict__ batch, int* __restrict__ goff) {
  int g = blockIdx.x * 256 + threadIdx.x;
  if (g > BB) return;
  int lo = 0, hi = NN;
  while (lo < hi) {
    int mid = (lo + hi) >> 1;
    if (batch[mid] < g) lo = mid + 1; else hi = mid;
  }
  goff[g] = lo;
}

// ---------------- fused NNConv message kernel ----------------
// Block: 4 src nodes. Phase 1: wave w computes G[n][k][f] for k in [w*32,w*32+32), all 4 nodes
//   (h of 4 nodes packed-bf16 in VGPRs; Wn2r rows read as contiguous 16B vectors).
//   G stored bf16-packed in LDS with XOR-swizzled kp index (64 KB exactly, conflict-free).
// Phase 2: wave w handles node n0+w's out-edges; msg = bias + sum_k hn1*G via dot2;
//   scatter with fp32 atomicAdd into aggr[dst].
__global__ __launch_bounds__(256, 2) void k_conv(
    const uint_t* __restrict__ hpk, const uint_t* __restrict__ hn1pk,
    const uint_t* __restrict__ Wn2r, const uint_t* __restrict__ bn2r,
    const int* __restrict__ rps, const int* __restrict__ eds,
    const int* __restrict__ ei, float* __restrict__ aggr) {
  __shared__ uint_t Gu[4][64][64];  // [n][f][kp ^ (f&31)] packed bf16 pairs along k — 64 KB
  const int tid = threadIdx.x;
  const int w = tid >> 6, f = tid & 63;
  const int fx = f & 31;
  const int n0 = blockIdx.x * 4;

  // ---- phase 1 ----
  {
    uint_t hv[4][32];  // 4 nodes' h rows, packed bf16 pairs (128 VGPRs)
#pragma unroll
    for (int n = 0; n < 4; ++n) {
      const uint4* hp = (const uint4*)(hpk + (size_t)(n0 + n) * 32);
#pragma unroll
      for (int j = 0; j < 8; ++j) {
        uint4 t = hp[j];
        hv[n][4 * j + 0] = t.x; hv[n][4 * j + 1] = t.y;
        hv[n][4 * j + 2] = t.z; hv[n][4 * j + 3] = t.w;
      }
    }
    const int kbase = w * 32;
#pragma unroll 1
    for (int k2 = 0; k2 < 16; ++k2) {
      const int k = kbase + 2 * k2;
      float a0[4] = {0.f, 0.f, 0.f, 0.f};
      float a1[4] = {0.f, 0.f, 0.f, 0.f};
      {
        const uint4* wp = (const uint4*)(Wn2r + ((size_t)k * 64 + f) * 32);
#pragma unroll
        for (int j = 0; j < 8; ++j) {
          uint4 wv = wp[j];
#pragma unroll
          for (int n = 0; n < 4; ++n) {
            a0[n] = dot2a(wv.x, hv[n][4 * j + 0], a0[n]);
            a0[n] = dot2a(wv.y, hv[n][4 * j + 1], a0[n]);
            a0[n] = dot2a(wv.z, hv[n][4 * j + 2], a0[n]);
            a0[n] = dot2a(wv.w, hv[n][4 * j + 3], a0[n]);
          }
        }
      }
      {
        const uint4* wp = (const uint4*)(Wn2r + ((size_t)(k + 1) * 64 + f) * 32);
#pragma unroll
        for (int j = 0; j < 8; ++j) {
          uint4 wv = wp[j];
#pragma unroll
          for (int n = 0; n < 4; ++n) {
            a1[n] = dot2a(wv.x, hv[n][4 * j + 0], a1[n]);
            a1[n] = dot2a(wv.y, hv[n][4 * j + 1], a1[n]);
            a1[n] = dot2a(wv.z, hv[n][4 * j + 2], a1[n]);
            a1[n] = dot2a(wv.w, hv[n][4 * j + 3], a1[n]);
          }
        }
      }
      const int kpix = (kbase >> 1) + k2;
#pragma unroll
      for (int n = 0; n < 4; ++n)
        Gu[n][f][kpix ^ fx] = (uint_t)f2bf(a0[n]) | ((uint_t)f2bf(a1[n]) << 16);
    }
  }
  __syncthreads();

  // ---- phase 2 ----
  const int n = n0 + w;
  float bias = 0.f;
  {
    const uint4* bp = (const uint4*)(bn2r + (size_t)f * 32);
    const uint4* hp = (const uint4*)(hpk + (size_t)n * 32);
#pragma unroll
    for (int j = 0; j < 8; ++j) {
      uint4 bv = bp[j]; uint4 hv4 = hp[j];
      bias = dot2a(bv.x, hv4.x, bias);
      bias = dot2a(bv.y, hv4.y, bias);
      bias = dot2a(bv.z, hv4.z, bias);
      bias = dot2a(bv.w, hv4.w, bias);
    }
  }
  uint_t Gr[64];
#pragma unroll
  for (int kp = 0; kp < 64; ++kp) Gr[kp] = Gu[w][f][kp ^ fx];

  const int i1 = rps[n + 1];
  for (int ii = rps[n]; ii < i1; ++ii) {
    const int e = eds[ii];
    const int dst = ei[EE + e];
    uint_t myh = hn1pk[(size_t)e * 64 + f];
    float m = bias;
#pragma unroll
    for (int kp = 0; kp < 64; ++kp)
      m = dot2a(Gr[kp], (uint_t)__shfl((int)myh, kp), m);
    atomicAdd(&aggr[(size_t)dst * 64 + f], m);
  }
}

// ---------------- h update: residual + aggr + root GEMM; writes h and hpk ----------------
__global__ void k_update(float* __restrict__ h, uint_t* __restrict__ hpk,
                         const float* __restrict__ aggr,
                         const float* __restrict__ root, const float* __restrict__ cb, int l) {
  __shared__ float hl[DD];
  const int n = blockIdx.x, f = threadIdx.x;
  hl[f] = h[(size_t)n * DD + f];
  __syncthreads();
  float acc = hl[f] + aggr[(size_t)n * DD + f] + cb[l * DD + f];
  const float* rp = root + (size_t)l * DD2 + f;
#pragma unroll
  for (int d = 0; d < DD; ++d) acc += hl[d] * rp[d * DD];
  h[(size_t)n * DD + f] = acc;
  float other = __shfl_down(acc, 1);
  if ((f & 1) == 0)
    hpk[(size_t)n * 32 + (f >> 1)] = (uint_t)f2bf(acc) | ((uint_t)f2bf(other) << 16);
}

// ---------------- Set2Set LSTM step ----------------
__global__ void k_lstm(const float* __restrict__ qstar, float* __restrict__ hs, float* __restrict__ cs,
                       const float* __restrict__ Wih, const float* __restrict__ Whh,
                       const float* __restrict__ lb) {
  __shared__ float qs[K1];
  __shared__ float hsl[DD];
  const int b = blockIdx.x, d = threadIdx.x;
  hsl[d] = hs[(size_t)b * DD + d];
  qs[d] = qstar[(size_t)b * K1 + d];
  qs[DD + d] = qstar[(size_t)b * K1 + DD + d];
  __syncthreads();
  float g4[4];
  for (int gi = 0; gi < 4; ++gi) {
    const int j = gi * DD + d;
    float a = lb[j];
    const float* wi = Wih + (size_t)j * K1;
    const float* wh = Whh + (size_t)j * DD;
    for (int i = 0; i < K1; ++i) a += qs[i] * wi[i];
    for (int i = 0; i < DD; ++i) a += hsl[i] * wh[i];
    g4[gi] = a;
  }
  float ig = sigmf_(g4[0]), fg = sigmf_(g4[1]), gg = tanhf(g4[2]), og = sigmf_(g4[3]);
  float c = fg * cs[(size_t)b * DD + d] + ig * gg;
  cs[(size_t)b * DD + d] = c;
  hs[(size_t)b * DD + d] = og * tanhf(c);
}

// ---------------- Set2Set attention + readout, one block per graph ----------------
#define EVCAP 2048
__global__ void k_attn(const float* __restrict__ h, const float* __restrict__ hs,
                       const int* __restrict__ goff, float* __restrict__ qstar) {
  __shared__ float q[DD];
  __shared__ float red[256];
  __shared__ float ev[EVCAP];
  __shared__ float rp[4][DD];
  const int g = blockIdx.x, tid = threadIdx.x;
  if (tid < DD) q[tid] = hs[(size_t)g * DD + tid];
  __syncthreads();
  const int i0 = goff[g];
  int cnt = goff[g + 1] - i0;
  if (cnt > EVCAP) cnt = EVCAP;
  float lmax = -1e30f;
  for (int j = tid; j < cnt; j += 256) {
    const float* hp = h + (size_t)(i0 + j) * DD;
    float e = 0.f;
#pragma unroll
    for (int d = 0; d < DD; ++d) e += hp[d] * q[d];
    ev[j] = e;
    lmax = fmaxf(lmax, e);
  }
  red[tid] = lmax;
  __syncthreads();
  for (int s = 128; s > 0; s >>= 1) {
    if (tid < s) red[tid] = fmaxf(red[tid], red[tid + s]);
    __syncthreads();
  }
  const float emax = red[0];
  __syncthreads();
  float lsum = 0.f;
  for (int j = tid; j < cnt; j += 256) {
    float ex = expf(ev[j] - emax);
    ev[j] = ex;
    lsum += ex;
  }
  red[tid] = lsum;
  __syncthreads();
  for (int s = 128; s > 0; s >>= 1) {
    if (tid < s) red[tid] += red[tid + s];
    __syncthreads();
  }
  const float denom = red[0];
  const int f = tid & 63, grp = tid >> 6;
  float acc = 0.f;
  for (int j = grp; j < cnt; j += 4)
    acc += ev[j] * h[(size_t)(i0 + j) * DD + f];
  rp[grp][f] = acc;
  __syncthreads();
  if (tid < DD) {
    float r = rp[0][tid] + rp[1][tid] + rp[2][tid] + rp[3][tid];
    r = (cnt > 0 && denom > 0.f) ? r / denom : 0.f;
    qstar[(size_t)g * K1 + DD + tid] = r;
    qstar[(size_t)g * K1 + tid] = q[tid];
  }
}

// ---------------- output MLP ----------------
__global__ void k_out(const float* __restrict__ qstar,
                      const float* __restrict__ Wo1, const float* __restrict__ bo1,
                      const float* __restrict__ Wo2, const float* __restrict__ bo2,
                      void* __restrict__ outv, const int* __restrict__ flag) {
  __shared__ float qs[K1];
  const int b = blockIdx.x, d = threadIdx.x;
  qs[d] = qstar[(size_t)b * K1 + d];
  qs[DD + d] = qstar[(size_t)b * K1 + DD + d];
  __syncthreads();
  float t = bo1[d];
  for (int i = 0; i < K1; ++i) t += qs[i] * Wo1[i * DD + d];
  float s = siluf_(t) * Wo2[d];
  for (int off = 32; off > 0; off >>= 1) s += __shfl_down(s, off);
  if (d == 0) {
    float v = s + bo2[0];
    if (*flag) ((ushort_t*)outv)[b] = f2bf(v);
    else       ((float*)outv)[b] = v;
  }
}

extern "C" void kernel_launch(void* const* d_in, const int* in_sizes, int n_in,
                              void* d_out, int out_size, void* d_ws, size_t ws_size,
                              hipStream_t stream) {
  const void* x_r    = d_in[0];
  const int*  ei     = (const int*)d_in[1];
  const void* ea_r   = d_in[2];
  const int*  batch  = (const int*)d_in[3];
  const void* W0_r   = d_in[4];
  const void* b0_r   = d_in[5];
  const void* Wn1_r  = d_in[6];
  const void* bn1_r  = d_in[7];
  const void* Wn2_r  = d_in[8];
  const void* bn2_r  = d_in[9];
  const void* root_r = d_in[10];
  const void* cb_r   = d_in[11];
  const void* Wih_r  = d_in[12];
  const void* Whh_r  = d_in[13];
  const void* lb_r   = d_in[14];
  const void* Wo1_r  = d_in[15];
  const void* bo1_r  = d_in[16];
  const void* Wo2_r  = d_in[17];
  const void* bo2_r  = d_in[18];

  char* w = (char*)d_ws;
  size_t off = 0;
  auto alloc = [&](size_t bytes) -> void* {
    void* p = w + off;
    off = (off + bytes + 255) & ~(size_t)255;
    return p;
  };
  int* flag = (int*)alloc(4);
  float* xc    = (float*)alloc((size_t)NN * DIN_ * 4);
  float* eac   = (float*)alloc((size_t)EE * 4 * 4);
  float* W0c   = (float*)alloc((size_t)DIN_ * DD * 4);
  float* b0c   = (float*)alloc((size_t)DD * 4);
  float* Wn1c  = (float*)alloc((size_t)4 * K1 * 4);
  float* bn1c  = (float*)alloc((size_t)K1 * 4);
  float* bn2c  = (float*)alloc((size_t)DD2 * 4);
  float* rootc = (float*)alloc((size_t)LL * DD2 * 4);
  float* cbc   = (float*)alloc((size_t)LL * DD * 4);
  float* Wihc  = (float*)alloc((size_t)4 * DD * K1 * 4);
  float* Whhc  = (float*)alloc((size_t)4 * DD * DD * 4);
  float* lbc   = (float*)alloc((size_t)4 * DD * 4);
  float* Wo1c  = (float*)alloc((size_t)K1 * DD * 4);
  float* bo1c  = (float*)alloc((size_t)DD * 4);
  float* Wo2c  = (float*)alloc((size_t)DD * 4);
  float* bo2c  = (float*)alloc((size_t)4);
  uint_t* Wn2r = (uint_t*)alloc((size_t)K1 * 64 * 32 * 4);   // 1 MB
  uint_t* bn2r = (uint_t*)alloc((size_t)64 * 32 * 4);        // 8 KB
  float*  h    = (float*)alloc((size_t)NN * DD * 4);         // 2.56 MB
  uint_t* hpk  = (uint_t*)alloc((size_t)NN * 32 * 4);        // 1.28 MB
  uint_t* hn1pk= (uint_t*)alloc((size_t)EE * (K1 / 2) * 4);  // 10.24 MB
  float*  aggr = (float*)alloc((size_t)NN * DD * 4);         // 2.56 MB
  int* cnts  = (int*)alloc((size_t)2 * NN * 4);
  int* rps   = (int*)alloc((size_t)(NN + 1) * 4);
  int* eds   = (int*)alloc((size_t)EE * 4);
  int* goff  = (int*)alloc((size_t)(BB + 1) * 4);
  float* s2s = (float*)alloc((size_t)BB * 256 * 4);
  float* qstar = s2s;
  float* hs = s2s + (size_t)BB * K1;
  float* cs = hs + (size_t)BB * DD;

  int* cnt_s = cnts;
  int* cur_s = cnts + NN;

  hipMemsetAsync(cnts, 0, (size_t)2 * NN * 4, stream);
  hipMemsetAsync(s2s, 0, (size_t)BB * 256 * 4, stream);

  k_detect<<<1, 256, 0, stream>>>((const ushort_t*)ea_r, flag);

  CanonArgs ca;
  const void* srcs[NCANON] = {x_r, ea_r, W0_r, b0_r, Wn1_r, bn1_r, bn2_r, root_r,
                              cb_r, Wih_r, Whh_r, lb_r, Wo1_r, bo1_r, Wo2_r, bo2_r};
  float* dsts[NCANON] = {xc, eac, W0c, b0c, Wn1c, bn1c, bn2c, rootc,
                         cbc, Wihc, Whhc, lbc, Wo1c, bo1c, Wo2c, bo2c};
  int cnts_c[NCANON] = {NN * DIN_, EE * 4, DIN_ * DD, DD, 4 * K1, K1, DD2, LL * DD2,
                        LL * DD, 4 * DD * K1, 4 * DD * DD, 4 * DD, K1 * DD, DD, DD, 1};
  for (int i = 0; i < NCANON; ++i) { ca.src[i] = srcs[i]; ca.dst[i] = dsts[i]; ca.n[i] = cnts_c[i]; }
  {
    dim3 grid((EE * 4 + 255) / 256, NCANON);
    k_canon<<<grid, 256, 0, stream>>>(ca, flag);
  }
  k_wn2r<<<K1, 256, 0, stream>>>(Wn2_r, Wn2r, flag);
  k_bn2r<<<8, 256, 0, stream>>>(bn2c, bn2r);

  k_embed<<<(NN * 32 + 255) / 256, 256, 0, stream>>>(xc, W0c, b0c, h, hpk);
  k_edgemlp<<<(EE * (K1 / 2) + 255) / 256, 256, 0, stream>>>(eac, Wn1c, bn1c, hn1pk);
  k_hist<<<(EE + 255) / 256, 256, 0, stream>>>(ei, cnt_s);
  k_scan<<<1, 1024, 0, stream>>>(cnt_s, rps);
  k_fill<<<(EE + 255) / 256, 256, 0, stream>>>(ei, rps, cur_s, eds);
  k_goff<<<(BB + 1 + 255) / 256, 256, 0, stream>>>(batch, goff);

  for (int l = 0; l < LL; ++l) {
    hipMemsetAsync(aggr, 0, (size_t)NN * DD * 4, stream);
    k_conv<<<NN / 4, 256, 0, stream>>>(hpk, hn1pk, Wn2r, bn2r, rps, eds, ei, aggr);
    k_update<<<NN, DD, 0, stream>>>(h, hpk, aggr, rootc, cbc, l);
  }

  for (int m = 0; m < MM; ++m) {
    k_lstm<<<BB, DD, 0, stream>>>(qstar, hs, cs, Wihc, Whhc, lbc);
    k_attn<<<BB, 256, 0, stream>>>(h, hs, goff, qstar);
  }
  k_out<<<BB, DD, 0, stream>>>(qstar, Wo1c, bo1c, Wo2c, bo2c, d_out, flag);
}

// Round 4
// 824.936 us; speedup vs baseline: 8.0040x; 3.2647x over previous
//
#include <hip/hip_runtime.h>
#include <cstdint>
#include <cstddef>

#define NN   10000
#define EE   40000
#define DIN_ 11
#define DD   64
#define LL   4
#define BB   512
#define MM   3
#define K1   128   // 2*D
#define DD2  4096  // D*D

typedef unsigned short ushort_t;
typedef unsigned int   uint_t;

typedef __bf16 bf16x8_t __attribute__((ext_vector_type(8)));
typedef float  f32x4_t  __attribute__((ext_vector_type(4)));
union FragU { uint4 u; bf16x8_t b; };

__device__ __forceinline__ float bfu(ushort_t u) { return __uint_as_float(((uint_t)u) << 16); }
__device__ __forceinline__ float bflo(uint_t u) { return __uint_as_float(u << 16); }
__device__ __forceinline__ float bfhi(uint_t u) { return __uint_as_float(u & 0xffff0000u); }
__device__ __forceinline__ ushort_t f2bf(float f) {
  uint_t u = __float_as_uint(f);
  u = (u + 0x7fffu + ((u >> 16) & 1u)) >> 16;
  return (ushort_t)u;
}
__device__ __forceinline__ float sigmf_(float x) { return 1.f / (1.f + expf(-x)); }
__device__ __forceinline__ float siluf_(float x) { return x / (1.f + expf(-x)); }

// packed-bf16 pair dot product with fp32 accumulate (fallback if no dot2 HW builtin)
#if defined(__HIP_DEVICE_COMPILE__) && __has_builtin(__builtin_amdgcn_fdot2_f32_bf16)
typedef __bf16 bf16x2_t __attribute__((ext_vector_type(2)));
__device__ __forceinline__ float dot2a(uint_t a, uint_t b, float c) {
  union { uint_t u; bf16x2_t v; } ua, ub;
  ua.u = a; ub.u = b;
  return __builtin_amdgcn_fdot2_f32_bf16(ua.v, ub.v, c, false);
}
#else
__device__ __forceinline__ float dot2a(uint_t a, uint_t b, float c) {
  return c + bflo(a) * bflo(b) + bfhi(a) * bfhi(b);
}
#endif

// ---------------- dtype detect: edge_attr is uniform[0,1) ----------------
__global__ void k_detect(const ushort_t* __restrict__ ea, int* __restrict__ flag) {
  __shared__ int bad;
  if (threadIdx.x == 0) bad = 0;
  __syncthreads();
  ushort_t u = ea[threadIdx.x];
  if ((u & 0x8000u) || u > 0x3F80u) atomicAdd(&bad, 1);
  __syncthreads();
  if (threadIdx.x == 0) *flag = (bad == 0) ? 1 : 0;
}

// ---------------- canonicalize float inputs to fp32 in ws ----------------
#define NCANON 16
struct CanonArgs {
  const void* src[NCANON];
  float* dst[NCANON];
  int n[NCANON];
};
__global__ void k_canon(CanonArgs a, const int* __restrict__ flag) {
  const int ai = blockIdx.y;
  const int n = a.n[ai];
  const int i = blockIdx.x * 256 + threadIdx.x;
  if (i >= n) return;
  float v;
  if (*flag) v = bfu(((const ushort_t*)a.src[ai])[i]);
  else       v = ((const float*)a.src[ai])[i];
  a.dst[ai][i] = v;
}

// ---------------- Wn2 repack into MFMA B-fragment order ----------------
// Layout (uint index): ((((kpg*4+fc)*2+par)*2+hf)*64 + lane)*4 + jp
//   B[k = q*8+j][n = lane&15] for MFMA(16x16x32): element = Wn2[2*kpg+par][(hf*32+q*8+j)*64 + fc*16+n]
__global__ void k_wn2m(const void* __restrict__ Wn2, uint_t* __restrict__ out,
                       const int* __restrict__ flag) {
  int o = blockIdx.x * 256 + threadIdx.x;  // 262144 uints
  if (o >= 64 * 4 * 2 * 2 * 64 * 4) return;
  int jp = o & 3; int r = o >> 2;
  int lane = r & 63; r >>= 6;
  int hf = r & 1; r >>= 1;
  int par = r & 1; r >>= 1;
  int fc = r & 3; r >>= 2;
  int kpg = r;  // 0..63
  int q = lane >> 4, n = lane & 15;
  int d0 = hf * 32 + q * 8 + 2 * jp;
  int f = fc * 16 + n;
  int k = kpg * 2 + par;
  size_t c0 = (size_t)k * DD2 + d0 * 64 + f;
  size_t c1 = c0 + 64;  // d0+1
  uint_t lo, hi;
  if (*flag) {
    const ushort_t* s = (const ushort_t*)Wn2;
    lo = s[c0]; hi = s[c1];
  } else {
    const float* s = (const float*)Wn2;
    lo = f2bf(s[c0]); hi = f2bf(s[c1]);
  }
  out[o] = lo | (hi << 16);
}

// ---------------- node embed: h, hpk, nbias ----------------
__global__ void k_embed(const float* __restrict__ x, const float* __restrict__ W0,
                        const float* __restrict__ b0, const float* __restrict__ bn2,
                        float* __restrict__ h, uint_t* __restrict__ hpk,
                        float* __restrict__ nbias) {
  __shared__ float xs[DIN_];
  __shared__ float hl[DD];
  const int n = blockIdx.x, f = threadIdx.x;
  if (f < DIN_) xs[f] = x[n * DIN_ + f];
  __syncthreads();
  float a = b0[f];
  for (int i = 0; i < DIN_; ++i) a += xs[i] * W0[i * DD + f];
  h[(size_t)n * DD + f] = a;
  hl[f] = a;
  float other = __shfl_down(a, 1);
  if ((f & 1) == 0)
    hpk[(size_t)n * 32 + (f >> 1)] = (uint_t)f2bf(a) | ((uint_t)f2bf(other) << 16);
  __syncthreads();
  float nb = 0.f;
#pragma unroll
  for (int d = 0; d < DD; ++d) nb += hl[d] * bn2[d * DD + f];
  nbias[(size_t)n * DD + f] = nb;
}

// ---------------- edge MLP layer1: hn1 = silu(ea @ Wn1 + bn1), packed bf16 ----------------
__global__ void k_edgemlp(const float* __restrict__ ea, const float* __restrict__ Wn1,
                          const float* __restrict__ bn1, uint_t* __restrict__ hn1pk) {
  int idx = blockIdx.x * 256 + threadIdx.x;  // e*64 + j
  if (idx >= EE * (K1 / 2)) return;
  int e = idx >> 6, j = idx & 63;
  int k0 = 2 * j, k1 = 2 * j + 1;
  float a0 = ea[e * 4 + 0], a1 = ea[e * 4 + 1], a2 = ea[e * 4 + 2], a3 = ea[e * 4 + 3];
  float t0 = bn1[k0] + a0 * Wn1[k0] + a1 * Wn1[K1 + k0] + a2 * Wn1[2 * K1 + k0] + a3 * Wn1[3 * K1 + k0];
  float t1 = bn1[k1] + a0 * Wn1[k1] + a1 * Wn1[K1 + k1] + a2 * Wn1[2 * K1 + k1] + a3 * Wn1[3 * K1 + k1];
  hn1pk[idx] = (uint_t)f2bf(siluf_(t0)) | ((uint_t)f2bf(siluf_(t1)) << 16);
}

// ---------------- src-CSR build ----------------
__global__ void k_hist(const int* __restrict__ ei, int* __restrict__ cnt_s) {
  int e = blockIdx.x * 256 + threadIdx.x;
  if (e >= EE) return;
  atomicAdd(&cnt_s[ei[e]], 1);
}

__global__ void k_scan(const int* __restrict__ cnt, int* __restrict__ rp) {
  __shared__ int part[1024];
  const int tid = threadIdx.x;
  const int chunk = (NN + 1023) / 1024;
  int s = 0;
  for (int j = 0; j < chunk; ++j) {
    int idx = tid * chunk + j;
    if (idx < NN) s += cnt[idx];
  }
  part[tid] = s;
  __syncthreads();
  for (int off = 1; off < 1024; off <<= 1) {
    int v = (tid >= off) ? part[tid - off] : 0;
    __syncthreads();
    part[tid] += v;
    __syncthreads();
  }
  int base = (tid == 0) ? 0 : part[tid - 1];
  for (int j = 0; j < chunk; ++j) {
    int idx = tid * chunk + j;
    if (idx < NN) { rp[idx] = base; base += cnt[idx]; }
  }
  if (tid == 1023) rp[NN] = part[1023];
}

__global__ void k_fill(const int* __restrict__ ei, const int* __restrict__ rps,
                       int* __restrict__ cur_s, int* __restrict__ eds) {
  int e = blockIdx.x * 256 + threadIdx.x;
  if (e >= EE) return;
  int s = ei[e];
  int ps = atomicAdd(&cur_s[s], 1);
  eds[rps[s] + ps] = e;
}

// graph segment offsets from sorted batch
__global__ void k_goff(const int* __restrict__ batch, int* __restrict__ goff) {
  int g = blockIdx.x * 256 + threadIdx.x;
  if (g > BB) return;
  int lo = 0, hi = NN;
  while (lo < hi) {
    int mid = (lo + hi) >> 1;
    if (batch[mid] < g) lo = mid + 1; else hi = mid;
  }
  goff[g] = lo;
}

// ---------------- fused NNConv message kernel (MFMA) ----------------
// Block: 16 src nodes, 4 waves. K-space in 4 chunks of 32 k (16 pairs).
// Per chunk: phase 1 computes G[m][k][f] via mfma_f32_16x16x32_bf16
//   (A = h fragments, B = pre-repacked Wn2m), packs bf16 pairs into LDS [m][kp][f].
//   phase 2: per out-edge, lane f: partial += sum_kp dot2(hn1_pair, G_pair);
//   chunk 0 seeds with nbias[src]; every chunk atomicAdds into aggr[dst].
__global__ __launch_bounds__(256, 2) void k_conv(
    const uint_t* __restrict__ hpk, const uint_t* __restrict__ hn1pk,
    const uint_t* __restrict__ Wn2m, const float* __restrict__ nbias,
    const int* __restrict__ rps, const int* __restrict__ eds,
    const int* __restrict__ ei, float* __restrict__ aggr) {
  __shared__ uint_t Gp[16 * 16 * 64];  // [m][kp][f] packed bf16 pairs — 64 KB
  const int tid = threadIdx.x;
  const int w = tid >> 6, lane = tid & 63;
  const int q = lane >> 4, n16 = lane & 15;
  const int n0 = blockIdx.x * 16;

  // A fragments: lane holds h[n0+n16][hf*32 + q*8 .. +7]
  FragU a0, a1;
  {
    const uint4* ap = (const uint4*)(hpk + (size_t)(n0 + n16) * 32);
    a0.u = ap[q];
    a1.u = ap[4 + q];
  }
  const int e0 = rps[n0], e1 = rps[n0 + 16];

  for (int c = 0; c < 4; ++c) {
    if (c) __syncthreads();  // previous chunk's phase-2 reads done before overwrite
    // ---- phase 1: this wave covers chunk-local pairs kpl = w*4 .. w*4+3 ----
    for (int kk = 0; kk < 4; ++kk) {
      const int kpl = w * 4 + kk;
      const int kpg = c * 16 + kpl;
#pragma unroll
      for (int fc = 0; fc < 4; ++fc) {
        const uint4* bp = (const uint4*)Wn2m + (size_t)(kpg * 4 + fc) * 256 + lane;
        FragU b00, b01, b10, b11;
        b00.u = bp[0];    // par0 hf0
        b01.u = bp[64];   // par0 hf1
        b10.u = bp[128];  // par1 hf0
        b11.u = bp[192];  // par1 hf1
        f32x4_t acc0 = {0.f, 0.f, 0.f, 0.f};
        f32x4_t acc1 = {0.f, 0.f, 0.f, 0.f};
        acc0 = __builtin_amdgcn_mfma_f32_16x16x32_bf16(a0.b, b00.b, acc0, 0, 0, 0);
        acc0 = __builtin_amdgcn_mfma_f32_16x16x32_bf16(a1.b, b01.b, acc0, 0, 0, 0);
        acc1 = __builtin_amdgcn_mfma_f32_16x16x32_bf16(a0.b, b10.b, acc1, 0, 0, 0);
        acc1 = __builtin_amdgcn_mfma_f32_16x16x32_bf16(a1.b, b11.b, acc1, 0, 0, 0);
        // D: col(f) = lane&15, row(node m) = q*4 + r
#pragma unroll
        for (int r = 0; r < 4; ++r) {
          const int m = q * 4 + r;
          Gp[((size_t)m * 16 + kpl) * 64 + fc * 16 + n16] =
              (uint_t)f2bf(acc0[r]) | ((uint_t)f2bf(acc1[r]) << 16);
        }
      }
    }
    __syncthreads();
    // ---- phase 2 ----
    for (int ii = e0 + w; ii < e1; ii += 4) {
      int e = eds[ii];
      e = __builtin_amdgcn_readfirstlane(e);
      int src = ei[e];
      src = __builtin_amdgcn_readfirstlane(src);
      int dst = ei[EE + e];
      dst = __builtin_amdgcn_readfirstlane(dst);
      const int m = src - n0;
      float p = (c == 0) ? nbias[(size_t)src * 64 + lane] : 0.f;
      const uint_t* hp = hn1pk + (size_t)e * 64 + c * 16;
      const uint_t* gb = Gp + (size_t)m * 1024 + lane;
#pragma unroll
      for (int kp = 0; kp < 16; ++kp)
        p = dot2a(hp[kp], gb[kp * 64], p);
      atomicAdd(&aggr[(size_t)dst * 64 + lane], p);
    }
  }
}

// ---------------- h update: residual + aggr + root GEMM; writes h, hpk, nbias ----------------
__global__ void k_update(float* __restrict__ h, uint_t* __restrict__ hpk,
                         const float* __restrict__ aggr, const float* __restrict__ bn2,
                         const float* __restrict__ root, const float* __restrict__ cb,
                         float* __restrict__ nbias, int l) {
  __shared__ float hl[DD];
  const int n = blockIdx.x, f = threadIdx.x;
  hl[f] = h[(size_t)n * DD + f];
  __syncthreads();
  float acc = hl[f] + aggr[(size_t)n * DD + f] + cb[l * DD + f];
  const float* rp = root + (size_t)l * DD2 + f;
#pragma unroll
  for (int d = 0; d < DD; ++d) acc += hl[d] * rp[d * DD];
  h[(size_t)n * DD + f] = acc;
  float other = __shfl_down(acc, 1);
  if ((f & 1) == 0)
    hpk[(size_t)n * 32 + (f >> 1)] = (uint_t)f2bf(acc) | ((uint_t)f2bf(other) << 16);
  __syncthreads();
  hl[f] = acc;
  __syncthreads();
  float nb = 0.f;
#pragma unroll
  for (int d = 0; d < DD; ++d) nb += hl[d] * bn2[d * DD + f];
  nbias[(size_t)n * DD + f] = nb;
}

// ---------------- Set2Set LSTM step ----------------
__global__ void k_lstm(const float* __restrict__ qstar, float* __restrict__ hs, float* __restrict__ cs,
                       const float* __restrict__ Wih, const float* __restrict__ Whh,
                       const float* __restrict__ lb) {
  __shared__ float qs[K1];
  __shared__ float hsl[DD];
  const int b = blockIdx.x, d = threadIdx.x;
  hsl[d] = hs[(size_t)b * DD + d];
  qs[d] = qstar[(size_t)b * K1 + d];
  qs[DD + d] = qstar[(size_t)b * K1 + DD + d];
  __syncthreads();
  float g4[4];
  for (int gi = 0; gi < 4; ++gi) {
    const int j = gi * DD + d;
    float a = lb[j];
    const float* wi = Wih + (size_t)j * K1;
    const float* wh = Whh + (size_t)j * DD;
    for (int i = 0; i < K1; ++i) a += qs[i] * wi[i];
    for (int i = 0; i < DD; ++i) a += hsl[i] * wh[i];
    g4[gi] = a;
  }
  float ig = sigmf_(g4[0]), fg = sigmf_(g4[1]), gg = tanhf(g4[2]), og = sigmf_(g4[3]);
  float c = fg * cs[(size_t)b * DD + d] + ig * gg;
  cs[(size_t)b * DD + d] = c;
  hs[(size_t)b * DD + d] = og * tanhf(c);
}

// ---------------- Set2Set attention + readout, one block per graph ----------------
#define EVCAP 2048
__global__ void k_attn(const float* __restrict__ h, const float* __restrict__ hs,
                       const int* __restrict__ goff, float* __restrict__ qstar) {
  __shared__ float q[DD];
  __shared__ float red[256];
  __shared__ float ev[EVCAP];
  __shared__ float rp[4][DD];
  const int g = blockIdx.x, tid = threadIdx.x;
  if (tid < DD) q[tid] = hs[(size_t)g * DD + tid];
  __syncthreads();
  const int i0 = goff[g];
  int cnt = goff[g + 1] - i0;
  if (cnt > EVCAP) cnt = EVCAP;
  float lmax = -1e30f;
  for (int j = tid; j < cnt; j += 256) {
    const float* hp = h + (size_t)(i0 + j) * DD;
    float e = 0.f;
#pragma unroll
    for (int d = 0; d < DD; ++d) e += hp[d] * q[d];
    ev[j] = e;
    lmax = fmaxf(lmax, e);
  }
  red[tid] = lmax;
  __syncthreads();
  for (int s = 128; s > 0; s >>= 1) {
    if (tid < s) red[tid] = fmaxf(red[tid], red[tid + s]);
    __syncthreads();
  }
  const float emax = red[0];
  __syncthreads();
  float lsum = 0.f;
  for (int j = tid; j < cnt; j += 256) {
    float ex = expf(ev[j] - emax);
    ev[j] = ex;
    lsum += ex;
  }
  red[tid] = lsum;
  __syncthreads();
  for (int s = 128; s > 0; s >>= 1) {
    if (tid < s) red[tid] += red[tid + s];
    __syncthreads();
  }
  const float denom = red[0];
  const int f = tid & 63, grp = tid >> 6;
  float acc = 0.f;
  for (int j = grp; j < cnt; j += 4)
    acc += ev[j] * h[(size_t)(i0 + j) * DD + f];
  rp[grp][f] = acc;
  __syncthreads();
  if (tid < DD) {
    float r = rp[0][tid] + rp[1][tid] + rp[2][tid] + rp[3][tid];
    r = (cnt > 0 && denom > 0.f) ? r / denom : 0.f;
    qstar[(size_t)g * K1 + DD + tid] = r;
    qstar[(size_t)g * K1 + tid] = q[tid];
  }
}

// ---------------- output MLP ----------------
__global__ void k_out(const float* __restrict__ qstar,
                      const float* __restrict__ Wo1, const float* __restrict__ bo1,
                      const float* __restrict__ Wo2, const float* __restrict__ bo2,
                      void* __restrict__ outv, const int* __restrict__ flag) {
  __shared__ float qs[K1];
  const int b = blockIdx.x, d = threadIdx.x;
  qs[d] = qstar[(size_t)b * K1 + d];
  qs[DD + d] = qstar[(size_t)b * K1 + DD + d];
  __syncthreads();
  float t = bo1[d];
  for (int i = 0; i < K1; ++i) t += qs[i] * Wo1[i * DD + d];
  float s = siluf_(t) * Wo2[d];
  for (int off = 32; off > 0; off >>= 1) s += __shfl_down(s, off);
  if (d == 0) {
    float v = s + bo2[0];
    if (*flag) ((ushort_t*)outv)[b] = f2bf(v);
    else       ((float*)outv)[b] = v;
  }
}

extern "C" void kernel_launch(void* const* d_in, const int* in_sizes, int n_in,
                              void* d_out, int out_size, void* d_ws, size_t ws_size,
                              hipStream_t stream) {
  const void* x_r    = d_in[0];
  const int*  ei     = (const int*)d_in[1];
  const void* ea_r   = d_in[2];
  const int*  batch  = (const int*)d_in[3];
  const void* W0_r   = d_in[4];
  const void* b0_r   = d_in[5];
  const void* Wn1_r  = d_in[6];
  const void* bn1_r  = d_in[7];
  const void* Wn2_r  = d_in[8];
  const void* bn2_r  = d_in[9];
  const void* root_r = d_in[10];
  const void* cb_r   = d_in[11];
  const void* Wih_r  = d_in[12];
  const void* Whh_r  = d_in[13];
  const void* lb_r   = d_in[14];
  const void* Wo1_r  = d_in[15];
  const void* bo1_r  = d_in[16];
  const void* Wo2_r  = d_in[17];
  const void* bo2_r  = d_in[18];

  char* w = (char*)d_ws;
  size_t off = 0;
  auto alloc = [&](size_t bytes) -> void* {
    void* p = w + off;
    off = (off + bytes + 255) & ~(size_t)255;
    return p;
  };
  int* flag = (int*)alloc(4);
  float* xc    = (float*)alloc((size_t)NN * DIN_ * 4);
  float* eac   = (float*)alloc((size_t)EE * 4 * 4);
  float* W0c   = (float*)alloc((size_t)DIN_ * DD * 4);
  float* b0c   = (float*)alloc((size_t)DD * 4);
  float* Wn1c  = (float*)alloc((size_t)4 * K1 * 4);
  float* bn1c  = (float*)alloc((size_t)K1 * 4);
  float* bn2c  = (float*)alloc((size_t)DD2 * 4);
  float* rootc = (float*)alloc((size_t)LL * DD2 * 4);
  float* cbc   = (float*)alloc((size_t)LL * DD * 4);
  float* Wihc  = (float*)alloc((size_t)4 * DD * K1 * 4);
  float* Whhc  = (float*)alloc((size_t)4 * DD * DD * 4);
  float* lbc   = (float*)alloc((size_t)4 * DD * 4);
  float* Wo1c  = (float*)alloc((size_t)K1 * DD * 4);
  float* bo1c  = (float*)alloc((size_t)DD * 4);
  float* Wo2c  = (float*)alloc((size_t)DD * 4);
  float* bo2c  = (float*)alloc((size_t)4);
  uint_t* Wn2m = (uint_t*)alloc((size_t)64 * 4 * 2 * 2 * 64 * 4 * 4);  // 1 MB
  float*  h    = (float*)alloc((size_t)NN * DD * 4);          // 2.56 MB
  uint_t* hpk  = (uint_t*)alloc((size_t)NN * 32 * 4);         // 1.28 MB
  uint_t* hn1pk= (uint_t*)alloc((size_t)EE * (K1 / 2) * 4);   // 10.24 MB
  float*  aggr = (float*)alloc((size_t)NN * DD * 4);          // 2.56 MB
  float*  nbias= (float*)alloc((size_t)NN * DD * 4);          // 2.56 MB
  int* cnts  = (int*)alloc((size_t)2 * NN * 4);
  int* rps   = (int*)alloc((size_t)(NN + 1) * 4);
  int* eds   = (int*)alloc((size_t)EE * 4);
  int* goff  = (int*)alloc((size_t)(BB + 1) * 4);
  float* s2s = (float*)alloc((size_t)BB * 256 * 4);
  float* qstar = s2s;
  float* hs = s2s + (size_t)BB * K1;
  float* cs = hs + (size_t)BB * DD;

  int* cnt_s = cnts;
  int* cur_s = cnts + NN;

  hipMemsetAsync(cnts, 0, (size_t)2 * NN * 4, stream);
  hipMemsetAsync(s2s, 0, (size_t)BB * 256 * 4, stream);

  k_detect<<<1, 256, 0, stream>>>((const ushort_t*)ea_r, flag);

  CanonArgs ca;
  const void* srcs[NCANON] = {x_r, ea_r, W0_r, b0_r, Wn1_r, bn1_r, bn2_r, root_r,
                              cb_r, Wih_r, Whh_r, lb_r, Wo1_r, bo1_r, Wo2_r, bo2_r};
  float* dsts[NCANON] = {xc, eac, W0c, b0c, Wn1c, bn1c, bn2c, rootc,
                         cbc, Wihc, Whhc, lbc, Wo1c, bo1c, Wo2c, bo2c};
  int cnts_c[NCANON] = {NN * DIN_, EE * 4, DIN_ * DD, DD, 4 * K1, K1, DD2, LL * DD2,
                        LL * DD, 4 * DD * K1, 4 * DD * DD, 4 * DD, K1 * DD, DD, DD, 1};
  for (int i = 0; i < NCANON; ++i) { ca.src[i] = srcs[i]; ca.dst[i] = dsts[i]; ca.n[i] = cnts_c[i]; }
  {
    dim3 grid((EE * 4 + 255) / 256, NCANON);
    k_canon<<<grid, 256, 0, stream>>>(ca, flag);
  }
  k_wn2m<<<1024, 256, 0, stream>>>(Wn2_r, Wn2m, flag);

  k_embed<<<NN, DD, 0, stream>>>(xc, W0c, b0c, bn2c, h, hpk, nbias);
  k_edgemlp<<<(EE * (K1 / 2) + 255) / 256, 256, 0, stream>>>(eac, Wn1c, bn1c, hn1pk);
  k_hist<<<(EE + 255) / 256, 256, 0, stream>>>(ei, cnt_s);
  k_scan<<<1, 1024, 0, stream>>>(cnt_s, rps);
  k_fill<<<(EE + 255) / 256, 256, 0, stream>>>(ei, rps, cur_s, eds);
  k_goff<<<(BB + 1 + 255) / 256, 256, 0, stream>>>(batch, goff);

  for (int l = 0; l < LL; ++l) {
    hipMemsetAsync(aggr, 0, (size_t)NN * DD * 4, stream);
    k_conv<<<NN / 16, 256, 0, stream>>>(hpk, hn1pk, Wn2m, nbias, rps, eds, ei, aggr);
    k_update<<<NN, DD, 0, stream>>>(h, hpk, aggr, bn2c, rootc, cbc, nbias, l);
  }

  for (int m = 0; m < MM; ++m) {
    k_lstm<<<BB, DD, 0, stream>>>(qstar, hs, cs, Wihc, Whhc, lbc);
    k_attn<<<BB, 256, 0, stream>>>(h, hs, goff, qstar);
  }
  k_out<<<BB, DD, 0, stream>>>(qstar, Wo1c, bo1c, Wo2c, bo2c, d_out, flag);
}

// Round 5
// 632.877 us; speedup vs baseline: 10.4330x; 1.3035x over previous
//
#include <hip/hip_runtime.h>
#include <cstdint>
#include <cstddef>

#define NN   10000
#define EE   40000
#define DIN_ 11
#define DD   64
#define LL   4
#define BB   512
#define MM   3
#define K1   128   // 2*D
#define DD2  4096  // D*D

typedef unsigned short ushort_t;
typedef unsigned int   uint_t;

typedef __bf16 bf16x8_t __attribute__((ext_vector_type(8)));
typedef float  f32x4_t  __attribute__((ext_vector_type(4)));
union FragU { uint4 u; bf16x8_t b; };

__device__ __forceinline__ float bfu(ushort_t u) { return __uint_as_float(((uint_t)u) << 16); }
__device__ __forceinline__ float bflo(uint_t u) { return __uint_as_float(u << 16); }
__device__ __forceinline__ float bfhi(uint_t u) { return __uint_as_float(u & 0xffff0000u); }
__device__ __forceinline__ ushort_t f2bf(float f) {
  uint_t u = __float_as_uint(f);
  u = (u + 0x7fffu + ((u >> 16) & 1u)) >> 16;
  return (ushort_t)u;
}
__device__ __forceinline__ float sigmf_(float x) { return 1.f / (1.f + expf(-x)); }
__device__ __forceinline__ float siluf_(float x) { return x / (1.f + expf(-x)); }

#if defined(__HIP_DEVICE_COMPILE__) && __has_builtin(__builtin_amdgcn_fdot2_f32_bf16)
typedef __bf16 bf16x2_t __attribute__((ext_vector_type(2)));
__device__ __forceinline__ float dot2a(uint_t a, uint_t b, float c) {
  union { uint_t u; bf16x2_t v; } ua, ub;
  ua.u = a; ub.u = b;
  return __builtin_amdgcn_fdot2_f32_bf16(ua.v, ub.v, c, false);
}
#else
__device__ __forceinline__ float dot2a(uint_t a, uint_t b, float c) {
  return c + bflo(a) * bflo(b) + bfhi(a) * bfhi(b);
}
#endif

// ---------------- dtype detect: edge_attr is uniform[0,1) ----------------
__global__ void k_detect(const ushort_t* __restrict__ ea, int* __restrict__ flag) {
  __shared__ int bad;
  if (threadIdx.x == 0) bad = 0;
  __syncthreads();
  ushort_t u = ea[threadIdx.x];
  if ((u & 0x8000u) || u > 0x3F80u) atomicAdd(&bad, 1);
  __syncthreads();
  if (threadIdx.x == 0) *flag = (bad == 0) ? 1 : 0;
}

// ---------------- canonicalize float inputs to fp32 in ws ----------------
#define NCANON 16
struct CanonArgs {
  const void* src[NCANON];
  float* dst[NCANON];
  int n[NCANON];
};
__global__ void k_canon(CanonArgs a, const int* __restrict__ flag) {
  const int ai = blockIdx.y;
  const int n = a.n[ai];
  const int i = blockIdx.x * 256 + threadIdx.x;
  if (i >= n) return;
  float v;
  if (*flag) v = bfu(((const ushort_t*)a.src[ai])[i]);
  else       v = ((const float*)a.src[ai])[i];
  a.dst[ai][i] = v;
}

// ---------------- Wn2 repack into MFMA B-fragment order ----------------
// uint index: ((((kpg*4+fc)*2+par)*2+hf)*64 + lane)*4 + jp
//   B[k=q*8+j][n=lane&15] for MFMA 16x16x32: element = Wn2[2*kpg+par][(hf*32+q*8+j)*64 + fc*16+n]
__global__ void k_wn2m(const void* __restrict__ Wn2, uint_t* __restrict__ out,
                       const int* __restrict__ flag) {
  int o = blockIdx.x * 256 + threadIdx.x;  // 262144 uints
  if (o >= 64 * 4 * 2 * 2 * 64 * 4) return;
  int jp = o & 3; int r = o >> 2;
  int lane = r & 63; r >>= 6;
  int hf = r & 1; r >>= 1;
  int par = r & 1; r >>= 1;
  int fc = r & 3; r >>= 2;
  int kpg = r;  // 0..63
  int q = lane >> 4, n = lane & 15;
  int d0 = hf * 32 + q * 8 + 2 * jp;
  int f = fc * 16 + n;
  int k = kpg * 2 + par;
  size_t c0 = (size_t)k * DD2 + d0 * 64 + f;
  size_t c1 = c0 + 64;
  uint_t lo, hi;
  if (*flag) {
    const ushort_t* s = (const ushort_t*)Wn2;
    lo = s[c0]; hi = s[c1];
  } else {
    const float* s = (const float*)Wn2;
    lo = f2bf(s[c0]); hi = f2bf(s[c1]);
  }
  out[o] = lo | (hi << 16);
}

// ---------------- node embed: h, hpk, nbias ----------------
__global__ void k_embed(const float* __restrict__ x, const float* __restrict__ W0,
                        const float* __restrict__ b0, const float* __restrict__ bn2,
                        float* __restrict__ h, uint_t* __restrict__ hpk,
                        float* __restrict__ nbias) {
  __shared__ float xs[DIN_];
  __shared__ float hl[DD];
  const int n = blockIdx.x, f = threadIdx.x;
  if (f < DIN_) xs[f] = x[n * DIN_ + f];
  __syncthreads();
  float a = b0[f];
  for (int i = 0; i < DIN_; ++i) a += xs[i] * W0[i * DD + f];
  h[(size_t)n * DD + f] = a;
  hl[f] = a;
  float other = __shfl_down(a, 1);
  if ((f & 1) == 0)
    hpk[(size_t)n * 32 + (f >> 1)] = (uint_t)f2bf(a) | ((uint_t)f2bf(other) << 16);
  __syncthreads();
  float nb = 0.f;
#pragma unroll
  for (int d = 0; d < DD; ++d) nb += hl[d] * bn2[d * DD + f];
  nbias[(size_t)n * DD + f] = nb;
}

// ---------------- edge MLP layer1, written in src-CSR order via epos ----------------
__global__ void k_edgemlp(const float* __restrict__ ea, const float* __restrict__ Wn1,
                          const float* __restrict__ bn1, const int* __restrict__ epos,
                          uint_t* __restrict__ hn1s) {
  int idx = blockIdx.x * 256 + threadIdx.x;  // e*64 + j
  if (idx >= EE * (K1 / 2)) return;
  int e = idx >> 6, j = idx & 63;
  int k0 = 2 * j, k1 = 2 * j + 1;
  float a0 = ea[e * 4 + 0], a1 = ea[e * 4 + 1], a2 = ea[e * 4 + 2], a3 = ea[e * 4 + 3];
  float t0 = bn1[k0] + a0 * Wn1[k0] + a1 * Wn1[K1 + k0] + a2 * Wn1[2 * K1 + k0] + a3 * Wn1[3 * K1 + k0];
  float t1 = bn1[k1] + a0 * Wn1[k1] + a1 * Wn1[K1 + k1] + a2 * Wn1[2 * K1 + k1] + a3 * Wn1[3 * K1 + k1];
  int pos = epos[e];
  hn1s[(size_t)pos * 64 + j] = (uint_t)f2bf(siluf_(t0)) | ((uint_t)f2bf(siluf_(t1)) << 16);
}

// ---------------- src-CSR build ----------------
__global__ void k_hist(const int* __restrict__ ei, int* __restrict__ cnt_s) {
  int e = blockIdx.x * 256 + threadIdx.x;
  if (e >= EE) return;
  atomicAdd(&cnt_s[ei[e]], 1);
}

__global__ void k_scan(const int* __restrict__ cnt, int* __restrict__ rp) {
  __shared__ int part[1024];
  const int tid = threadIdx.x;
  const int chunk = (NN + 1023) / 1024;
  int s = 0;
  for (int j = 0; j < chunk; ++j) {
    int idx = tid * chunk + j;
    if (idx < NN) s += cnt[idx];
  }
  part[tid] = s;
  __syncthreads();
  for (int off = 1; off < 1024; off <<= 1) {
    int v = (tid >= off) ? part[tid - off] : 0;
    __syncthreads();
    part[tid] += v;
    __syncthreads();
  }
  int base = (tid == 0) ? 0 : part[tid - 1];
  for (int j = 0; j < chunk; ++j) {
    int idx = tid * chunk + j;
    if (idx < NN) { rp[idx] = base; base += cnt[idx]; }
  }
  if (tid == 1023) rp[NN] = part[1023];
}

// epos[e] = CSR slot of edge e; esd[2*pos..] = (src, dst)
__global__ void k_fill(const int* __restrict__ ei, const int* __restrict__ rps,
                       int* __restrict__ cur_s, int* __restrict__ epos,
                       int* __restrict__ esd) {
  int e = blockIdx.x * 256 + threadIdx.x;
  if (e >= EE) return;
  int s = ei[e], d = ei[EE + e];
  int ps = atomicAdd(&cur_s[s], 1);
  int pos = rps[s] + ps;
  epos[e] = pos;
  esd[2 * pos] = s;
  esd[2 * pos + 1] = d;
}

// graph segment offsets from sorted batch
__global__ void k_goff(const int* __restrict__ batch, int* __restrict__ goff) {
  int g = blockIdx.x * 256 + threadIdx.x;
  if (g > BB) return;
  int lo = 0, hi = NN;
  while (lo < hi) {
    int mid = (lo + hi) >> 1;
    if (batch[mid] < g) lo = mid + 1; else hi = mid;
  }
  goff[g] = lo;
}

// ---------------- fused NNConv message kernel (MFMA) ----------------
// Block: 16 src nodes, 4 waves, K in 4 chunks of 32.
// Phase 1: G chunk via mfma_f32_16x16x32_bf16 -> LDS (packed bf16 pairs).
// Phase 2: edges in CSR order; all addresses induction-derived (no dependent chains);
//          per-chunk partial atomicAdd into aggr[dst].
__global__ __launch_bounds__(256, 2) void k_conv(
    const uint_t* __restrict__ hpk, const uint_t* __restrict__ hn1s,
    const uint_t* __restrict__ Wn2m, const float* __restrict__ nbias,
    const int* __restrict__ rps, const int* __restrict__ esd,
    float* __restrict__ aggr) {
  __shared__ uint_t Gp[16 * 16 * 64];  // [m][kp][f] packed bf16 pairs — 64 KB
  const int tid = threadIdx.x;
  const int w = tid >> 6, lane = tid & 63;
  const int q = lane >> 4, n16 = lane & 15;
  const int n0 = blockIdx.x * 16;

  FragU a0, a1;
  {
    const uint4* ap = (const uint4*)(hpk + (size_t)(n0 + n16) * 32);
    a0.u = ap[q];
    a1.u = ap[4 + q];
  }
  const int e0 = rps[n0], e1 = rps[n0 + 16];

  for (int c = 0; c < 4; ++c) {
    if (c) __syncthreads();
    // ---- phase 1 ----
    for (int kk = 0; kk < 4; ++kk) {
      const int kpl = w * 4 + kk;
      const int kpg = c * 16 + kpl;
#pragma unroll
      for (int fc = 0; fc < 4; ++fc) {
        const uint4* bp = (const uint4*)Wn2m + (size_t)(kpg * 4 + fc) * 256 + lane;
        FragU b00, b01, b10, b11;
        b00.u = bp[0];
        b01.u = bp[64];
        b10.u = bp[128];
        b11.u = bp[192];
        f32x4_t acc0 = {0.f, 0.f, 0.f, 0.f};
        f32x4_t acc1 = {0.f, 0.f, 0.f, 0.f};
        acc0 = __builtin_amdgcn_mfma_f32_16x16x32_bf16(a0.b, b00.b, acc0, 0, 0, 0);
        acc0 = __builtin_amdgcn_mfma_f32_16x16x32_bf16(a1.b, b01.b, acc0, 0, 0, 0);
        acc1 = __builtin_amdgcn_mfma_f32_16x16x32_bf16(a0.b, b10.b, acc1, 0, 0, 0);
        acc1 = __builtin_amdgcn_mfma_f32_16x16x32_bf16(a1.b, b11.b, acc1, 0, 0, 0);
#pragma unroll
        for (int r = 0; r < 4; ++r) {
          const int m = q * 4 + r;
          Gp[((size_t)m * 16 + kpl) * 64 + fc * 16 + n16] =
              (uint_t)f2bf(acc0[r]) | ((uint_t)f2bf(acc1[r]) << 16);
        }
      }
    }
    __syncthreads();
    // ---- phase 2 ----
    for (int ii = e0 + w; ii < e1; ii += 4) {
      const int iiu = __builtin_amdgcn_readfirstlane(ii);
      const int src = __builtin_amdgcn_readfirstlane(esd[2 * iiu]);
      const int dst = __builtin_amdgcn_readfirstlane(esd[2 * iiu + 1]);
      const int m = src - n0;
      float p = (c == 0) ? nbias[(size_t)src * 64 + lane] : 0.f;
      const uint_t* hp = hn1s + (size_t)iiu * 64 + c * 16;
      const uint_t* gb = Gp + (size_t)m * 1024 + lane;
#pragma unroll
      for (int kp = 0; kp < 16; ++kp)
        p = dot2a(hp[kp], gb[kp * 64], p);
      atomicAdd(&aggr[(size_t)dst * 64 + lane], p);
    }
  }
}

// ---------------- h update: residual + aggr + root GEMM; re-zeros aggr ----------------
__global__ void k_update(float* __restrict__ h, uint_t* __restrict__ hpk,
                         float* __restrict__ aggr, const float* __restrict__ bn2,
                         const float* __restrict__ root, const float* __restrict__ cb,
                         float* __restrict__ nbias, int l) {
  __shared__ float hl[DD];
  const int n = blockIdx.x, f = threadIdx.x;
  hl[f] = h[(size_t)n * DD + f];
  __syncthreads();
  float acc = hl[f] + aggr[(size_t)n * DD + f] + cb[l * DD + f];
  aggr[(size_t)n * DD + f] = 0.f;  // re-zero for next layer
  const float* rp = root + (size_t)l * DD2 + f;
#pragma unroll
  for (int d = 0; d < DD; ++d) acc += hl[d] * rp[d * DD];
  h[(size_t)n * DD + f] = acc;
  float other = __shfl_down(acc, 1);
  if ((f & 1) == 0)
    hpk[(size_t)n * 32 + (f >> 1)] = (uint_t)f2bf(acc) | ((uint_t)f2bf(other) << 16);
  __syncthreads();
  hl[f] = acc;
  __syncthreads();
  float nb = 0.f;
#pragma unroll
  for (int d = 0; d < DD; ++d) nb += hl[d] * bn2[d * DD + f];
  nbias[(size_t)n * DD + f] = nb;
}

// ---------------- fused Set2Set (3x LSTM+attention) + output MLP ----------------
#define EVCAP 2048
__global__ void k_s2s(const float* __restrict__ h, const int* __restrict__ goff,
                      const float* __restrict__ Wih, const float* __restrict__ Whh,
                      const float* __restrict__ lb,
                      const float* __restrict__ Wo1, const float* __restrict__ bo1,
                      const float* __restrict__ Wo2, const float* __restrict__ bo2,
                      void* __restrict__ outv, const int* __restrict__ flag) {
  __shared__ float qsl[K1];
  __shared__ float hsl[DD];
  __shared__ float csl[DD];
  __shared__ float gl[4][DD];
  __shared__ float red[256];
  __shared__ float ev[EVCAP];
  __shared__ float rp4[4][DD];
  const int g = blockIdx.x, tid = threadIdx.x;

  if (tid < K1) qsl[tid] = 0.f;
  else if (tid < K1 + DD) hsl[tid - K1] = 0.f;
  else csl[tid - K1 - DD] = 0.f;
  __syncthreads();

  const int i0 = goff[g];
  int cnt = goff[g + 1] - i0;
  if (cnt > EVCAP) cnt = EVCAP;

  for (int m = 0; m < MM; ++m) {
    // ---- LSTM: thread = gi*64 + d ----
    {
      const int gi = tid >> 6, d = tid & 63;
      const int j = gi * DD + d;
      float a = lb[j];
      const float* wi = Wih + (size_t)j * K1;
      const float* wh = Whh + (size_t)j * DD;
      for (int i = 0; i < K1; ++i) a += qsl[i] * wi[i];
      for (int i = 0; i < DD; ++i) a += hsl[i] * wh[i];
      gl[gi][d] = a;
    }
    __syncthreads();
    if (tid < DD) {
      float ig = sigmf_(gl[0][tid]), fg = sigmf_(gl[1][tid]);
      float gg = tanhf(gl[2][tid]), og = sigmf_(gl[3][tid]);
      float c = fg * csl[tid] + ig * gg;
      csl[tid] = c;
      hsl[tid] = og * tanhf(c);
    }
    __syncthreads();
    // ---- attention, q = hsl ----
    float lmax = -1e30f;
    for (int jj = tid; jj < cnt; jj += 256) {
      const float* hp = h + (size_t)(i0 + jj) * DD;
      float e = 0.f;
#pragma unroll
      for (int d = 0; d < DD; ++d) e += hp[d] * hsl[d];
      ev[jj] = e;
      lmax = fmaxf(lmax, e);
    }
    red[tid] = lmax;
    __syncthreads();
    for (int s = 128; s > 0; s >>= 1) {
      if (tid < s) red[tid] = fmaxf(red[tid], red[tid + s]);
      __syncthreads();
    }
    const float emax = red[0];
    __syncthreads();
    float lsum = 0.f;
    for (int jj = tid; jj < cnt; jj += 256) {
      float ex = expf(ev[jj] - emax);
      ev[jj] = ex;
      lsum += ex;
    }
    red[tid] = lsum;
    __syncthreads();
    for (int s = 128; s > 0; s >>= 1) {
      if (tid < s) red[tid] += red[tid + s];
      __syncthreads();
    }
    const float denom = red[0];
    const int f = tid & 63, grp = tid >> 6;
    float acc = 0.f;
    for (int jj = grp; jj < cnt; jj += 4)
      acc += ev[jj] * h[(size_t)(i0 + jj) * DD + f];
    rp4[grp][f] = acc;
    __syncthreads();
    if (tid < DD) {
      float r = rp4[0][tid] + rp4[1][tid] + rp4[2][tid] + rp4[3][tid];
      r = (cnt > 0 && denom > 0.f) ? r / denom : 0.f;
      qsl[tid] = hsl[tid];
      qsl[DD + tid] = r;
    }
    __syncthreads();
  }
  // ---- output MLP (first wave) ----
  if (tid < DD) {
    float t = bo1[tid];
    for (int i = 0; i < K1; ++i) t += qsl[i] * Wo1[i * DD + tid];
    float s = siluf_(t) * Wo2[tid];
    for (int off = 32; off > 0; off >>= 1) s += __shfl_down(s, off);
    if (tid == 0) {
      float v = s + bo2[0];
      if (*flag) ((ushort_t*)outv)[g] = f2bf(v);
      else       ((float*)outv)[g] = v;
    }
  }
}

extern "C" void kernel_launch(void* const* d_in, const int* in_sizes, int n_in,
                              void* d_out, int out_size, void* d_ws, size_t ws_size,
                              hipStream_t stream) {
  const void* x_r    = d_in[0];
  const int*  ei     = (const int*)d_in[1];
  const void* ea_r   = d_in[2];
  const int*  batch  = (const int*)d_in[3];
  const void* W0_r   = d_in[4];
  const void* b0_r   = d_in[5];
  const void* Wn1_r  = d_in[6];
  const void* bn1_r  = d_in[7];
  const void* Wn2_r  = d_in[8];
  const void* bn2_r  = d_in[9];
  const void* root_r = d_in[10];
  const void* cb_r   = d_in[11];
  const void* Wih_r  = d_in[12];
  const void* Whh_r  = d_in[13];
  const void* lb_r   = d_in[14];
  const void* Wo1_r  = d_in[15];
  const void* bo1_r  = d_in[16];
  const void* Wo2_r  = d_in[17];
  const void* bo2_r  = d_in[18];

  char* w = (char*)d_ws;
  size_t off = 0;
  auto alloc = [&](size_t bytes) -> void* {
    void* p = w + off;
    off = (off + bytes + 255) & ~(size_t)255;
    return p;
  };
  int* flag = (int*)alloc(4);
  float* xc    = (float*)alloc((size_t)NN * DIN_ * 4);
  float* eac   = (float*)alloc((size_t)EE * 4 * 4);
  float* W0c   = (float*)alloc((size_t)DIN_ * DD * 4);
  float* b0c   = (float*)alloc((size_t)DD * 4);
  float* Wn1c  = (float*)alloc((size_t)4 * K1 * 4);
  float* bn1c  = (float*)alloc((size_t)K1 * 4);
  float* bn2c  = (float*)alloc((size_t)DD2 * 4);
  float* rootc = (float*)alloc((size_t)LL * DD2 * 4);
  float* cbc   = (float*)alloc((size_t)LL * DD * 4);
  float* Wihc  = (float*)alloc((size_t)4 * DD * K1 * 4);
  float* Whhc  = (float*)alloc((size_t)4 * DD * DD * 4);
  float* lbc   = (float*)alloc((size_t)4 * DD * 4);
  float* Wo1c  = (float*)alloc((size_t)K1 * DD * 4);
  float* bo1c  = (float*)alloc((size_t)DD * 4);
  float* Wo2c  = (float*)alloc((size_t)DD * 4);
  float* bo2c  = (float*)alloc((size_t)4);
  uint_t* Wn2m = (uint_t*)alloc((size_t)64 * 4 * 2 * 2 * 64 * 4 * 4);  // 1 MB
  float*  h    = (float*)alloc((size_t)NN * DD * 4);          // 2.56 MB
  uint_t* hpk  = (uint_t*)alloc((size_t)NN * 32 * 4);         // 1.28 MB
  uint_t* hn1s = (uint_t*)alloc((size_t)EE * (K1 / 2) * 4);   // 10.24 MB (CSR order)
  float*  aggr = (float*)alloc((size_t)NN * DD * 4);          // 2.56 MB
  float*  nbias= (float*)alloc((size_t)NN * DD * 4);          // 2.56 MB
  int* cnts  = (int*)alloc((size_t)2 * NN * 4);
  int* rps   = (int*)alloc((size_t)(NN + 1) * 4);
  int* epos  = (int*)alloc((size_t)EE * 4);
  int* esd   = (int*)alloc((size_t)2 * EE * 4);
  int* goff  = (int*)alloc((size_t)(BB + 1) * 4);

  int* cnt_s = cnts;
  int* cur_s = cnts + NN;

  hipMemsetAsync(cnts, 0, (size_t)2 * NN * 4, stream);
  hipMemsetAsync(aggr, 0, (size_t)NN * DD * 4, stream);

  k_detect<<<1, 256, 0, stream>>>((const ushort_t*)ea_r, flag);

  CanonArgs ca;
  const void* srcs[NCANON] = {x_r, ea_r, W0_r, b0_r, Wn1_r, bn1_r, bn2_r, root_r,
                              cb_r, Wih_r, Whh_r, lb_r, Wo1_r, bo1_r, Wo2_r, bo2_r};
  float* dsts[NCANON] = {xc, eac, W0c, b0c, Wn1c, bn1c, bn2c, rootc,
                         cbc, Wihc, Whhc, lbc, Wo1c, bo1c, Wo2c, bo2c};
  int cnts_c[NCANON] = {NN * DIN_, EE * 4, DIN_ * DD, DD, 4 * K1, K1, DD2, LL * DD2,
                        LL * DD, 4 * DD * K1, 4 * DD * DD, 4 * DD, K1 * DD, DD, DD, 1};
  for (int i = 0; i < NCANON; ++i) { ca.src[i] = srcs[i]; ca.dst[i] = dsts[i]; ca.n[i] = cnts_c[i]; }
  {
    dim3 grid((EE * 4 + 255) / 256, NCANON);
    k_canon<<<grid, 256, 0, stream>>>(ca, flag);
  }
  k_wn2m<<<1024, 256, 0, stream>>>(Wn2_r, Wn2m, flag);

  k_embed<<<NN, DD, 0, stream>>>(xc, W0c, b0c, bn2c, h, hpk, nbias);
  k_hist<<<(EE + 255) / 256, 256, 0, stream>>>(ei, cnt_s);
  k_scan<<<1, 1024, 0, stream>>>(cnt_s, rps);
  k_fill<<<(EE + 255) / 256, 256, 0, stream>>>(ei, rps, cur_s, epos, esd);
  k_goff<<<(BB + 1 + 255) / 256, 256, 0, stream>>>(batch, goff);
  k_edgemlp<<<(EE * (K1 / 2) + 255) / 256, 256, 0, stream>>>(eac, Wn1c, bn1c, epos, hn1s);

  for (int l = 0; l < LL; ++l) {
    k_conv<<<NN / 16, 256, 0, stream>>>(hpk, hn1s, Wn2m, nbias, rps, esd, aggr);
    k_update<<<NN, DD, 0, stream>>>(h, hpk, aggr, bn2c, rootc, cbc, nbias, l);
  }

  k_s2s<<<BB, 256, 0, stream>>>(h, goff, Wihc, Whhc, lbc, Wo1c, bo1c, Wo2c, bo2c,
                                d_out, flag);
}

// Round 6
// 491.599 us; speedup vs baseline: 13.4312x; 1.2874x over previous
//
#include <hip/hip_runtime.h>
#include <cstdint>
#include <cstddef>

#define NN   10000
#define EE   40000
#define DIN_ 11
#define DD   64
#define LL   4
#define BB   512
#define MM   3
#define K1   128   // 2*D
#define DD2  4096  // D*D
#define NPB  10    // nodes per k_conv block (40 KB LDS -> 4 blocks/CU)

typedef unsigned short ushort_t;
typedef unsigned int   uint_t;

typedef __bf16 bf16x8_t __attribute__((ext_vector_type(8)));
typedef float  f32x4_t  __attribute__((ext_vector_type(4)));
union FragU { uint4 u; bf16x8_t b; };

__device__ __forceinline__ float bfu(ushort_t u) { return __uint_as_float(((uint_t)u) << 16); }
__device__ __forceinline__ float bflo(uint_t u) { return __uint_as_float(u << 16); }
__device__ __forceinline__ float bfhi(uint_t u) { return __uint_as_float(u & 0xffff0000u); }
__device__ __forceinline__ ushort_t f2bf(float f) {
  uint_t u = __float_as_uint(f);
  u = (u + 0x7fffu + ((u >> 16) & 1u)) >> 16;
  return (ushort_t)u;
}
__device__ __forceinline__ uint_t pack2(float lo, float hi) {
  return (uint_t)f2bf(lo) | ((uint_t)f2bf(hi) << 16);
}
__device__ __forceinline__ float sigmf_(float x) { return 1.f / (1.f + expf(-x)); }
__device__ __forceinline__ float siluf_(float x) { return x / (1.f + expf(-x)); }

#if defined(__HIP_DEVICE_COMPILE__) && __has_builtin(__builtin_amdgcn_fdot2_f32_bf16)
typedef __bf16 bf16x2_t __attribute__((ext_vector_type(2)));
__device__ __forceinline__ float dot2a(uint_t a, uint_t b, float c) {
  union { uint_t u; bf16x2_t v; } ua, ub;
  ua.u = a; ub.u = b;
  return __builtin_amdgcn_fdot2_f32_bf16(ua.v, ub.v, c, false);
}
#else
__device__ __forceinline__ float dot2a(uint_t a, uint_t b, float c) {
  return c + bflo(a) * bflo(b) + bfhi(a) * bfhi(b);
}
#endif

// ---------------- dtype detect: edge_attr is uniform[0,1) ----------------
__global__ void k_detect(const ushort_t* __restrict__ ea, int* __restrict__ flag) {
  __shared__ int bad;
  if (threadIdx.x == 0) bad = 0;
  __syncthreads();
  ushort_t u = ea[threadIdx.x];
  if ((u & 0x8000u) || u > 0x3F80u) atomicAdd(&bad, 1);
  __syncthreads();
  if (threadIdx.x == 0) *flag = (bad == 0) ? 1 : 0;
}

// ---------------- canonicalize float inputs to fp32 in ws ----------------
#define NCANON 16
struct CanonArgs {
  const void* src[NCANON];
  float* dst[NCANON];
  int n[NCANON];
};
__global__ void k_canon(CanonArgs a, const int* __restrict__ flag) {
  const int ai = blockIdx.y;
  const int n = a.n[ai];
  const int i = blockIdx.x * 256 + threadIdx.x;
  if (i >= n) return;
  float v;
  if (*flag) v = bfu(((const ushort_t*)a.src[ai])[i]);
  else       v = ((const float*)a.src[ai])[i];
  a.dst[ai][i] = v;
}

// ---------------- Wn2 repack into MFMA B-fragment order ----------------
// uint index: ((((kpg*4+fc)*2+par)*2+hf)*64 + lane)*4 + jp
//   B[k=q*8+j][n=lane&15] for MFMA 16x16x32: element = Wn2[2*kpg+par][(hf*32+q*8+j)*64 + fc*16+n]
__global__ void k_wn2m(const void* __restrict__ Wn2, uint_t* __restrict__ out,
                       const int* __restrict__ flag) {
  int o = blockIdx.x * 256 + threadIdx.x;  // 262144 uints
  if (o >= 64 * 4 * 2 * 2 * 64 * 4) return;
  int jp = o & 3; int r = o >> 2;
  int lane = r & 63; r >>= 6;
  int hf = r & 1; r >>= 1;
  int par = r & 1; r >>= 1;
  int fc = r & 3; r >>= 2;
  int kpg = r;  // 0..63
  int q = lane >> 4, n = lane & 15;
  int d0 = hf * 32 + q * 8 + 2 * jp;
  int f = fc * 16 + n;
  int k = kpg * 2 + par;
  size_t c0 = (size_t)k * DD2 + d0 * 64 + f;
  size_t c1 = c0 + 64;
  uint_t lo, hi;
  if (*flag) {
    const ushort_t* s = (const ushort_t*)Wn2;
    lo = s[c0]; hi = s[c1];
  } else {
    const float* s = (const float*)Wn2;
    lo = f2bf(s[c0]); hi = f2bf(s[c1]);
  }
  out[o] = lo | (hi << 16);
}

// ---------------- LSTM weight transpose: Wiht[i][j], Whht[i][j] ----------------
__global__ void k_wT(const float* __restrict__ Wihc, const float* __restrict__ Whhc,
                     float* __restrict__ Wiht, float* __restrict__ Whht) {
  int idx = blockIdx.x * 256 + threadIdx.x;
  if (idx < 4 * DD * K1) {
    int j = idx >> 7, i = idx & 127;  // Wihc[j][i]
    Wiht[i * 256 + j] = Wihc[idx];
  }
  if (idx < 4 * DD * DD) {
    int j = idx >> 6, i = idx & 63;   // Whhc[j][i]
    Whht[i * 256 + j] = Whhc[idx];
  }
}

// ---------------- node embed: h, hpk, nbias ----------------
__global__ void k_embed(const float* __restrict__ x, const float* __restrict__ W0,
                        const float* __restrict__ b0, const float* __restrict__ bn2,
                        float* __restrict__ h, uint_t* __restrict__ hpk,
                        float* __restrict__ nbias) {
  __shared__ float xs[DIN_];
  __shared__ float hl[DD];
  const int n = blockIdx.x, f = threadIdx.x;
  if (f < DIN_) xs[f] = x[n * DIN_ + f];
  __syncthreads();
  float a = b0[f];
  for (int i = 0; i < DIN_; ++i) a += xs[i] * W0[i * DD + f];
  h[(size_t)n * DD + f] = a;
  hl[f] = a;
  float other = __shfl_down(a, 1);
  if ((f & 1) == 0)
    hpk[(size_t)n * 32 + (f >> 1)] = pack2(a, other);
  __syncthreads();
  float nb = 0.f;
#pragma unroll
  for (int d = 0; d < DD; ++d) nb += hl[d] * bn2[d * DD + f];
  nbias[(size_t)n * DD + f] = nb;
}

// ---------------- edge MLP layer1, written in src-CSR order via epos ----------------
__global__ void k_edgemlp(const float* __restrict__ ea, const float* __restrict__ Wn1,
                          const float* __restrict__ bn1, const int* __restrict__ epos,
                          uint_t* __restrict__ hn1s) {
  int idx = blockIdx.x * 256 + threadIdx.x;  // e*64 + j
  if (idx >= EE * (K1 / 2)) return;
  int e = idx >> 6, j = idx & 63;
  int k0 = 2 * j, k1 = 2 * j + 1;
  float a0 = ea[e * 4 + 0], a1 = ea[e * 4 + 1], a2 = ea[e * 4 + 2], a3 = ea[e * 4 + 3];
  float t0 = bn1[k0] + a0 * Wn1[k0] + a1 * Wn1[K1 + k0] + a2 * Wn1[2 * K1 + k0] + a3 * Wn1[3 * K1 + k0];
  float t1 = bn1[k1] + a0 * Wn1[k1] + a1 * Wn1[K1 + k1] + a2 * Wn1[2 * K1 + k1] + a3 * Wn1[3 * K1 + k1];
  int pos = epos[e];
  hn1s[(size_t)pos * 64 + j] = pack2(siluf_(t0), siluf_(t1));
}

// ---------------- src-CSR build ----------------
__global__ void k_hist(const int* __restrict__ ei, int* __restrict__ cnt_s) {
  int e = blockIdx.x * 256 + threadIdx.x;
  if (e >= EE) return;
  atomicAdd(&cnt_s[ei[e]], 1);
}

__global__ void k_scan(const int* __restrict__ cnt, int* __restrict__ rp) {
  __shared__ int part[1024];
  const int tid = threadIdx.x;
  const int chunk = (NN + 1023) / 1024;
  int s = 0;
  for (int j = 0; j < chunk; ++j) {
    int idx = tid * chunk + j;
    if (idx < NN) s += cnt[idx];
  }
  part[tid] = s;
  __syncthreads();
  for (int off = 1; off < 1024; off <<= 1) {
    int v = (tid >= off) ? part[tid - off] : 0;
    __syncthreads();
    part[tid] += v;
    __syncthreads();
  }
  int base = (tid == 0) ? 0 : part[tid - 1];
  for (int j = 0; j < chunk; ++j) {
    int idx = tid * chunk + j;
    if (idx < NN) { rp[idx] = base; base += cnt[idx]; }
  }
  if (tid == 1023) rp[NN] = part[1023];
}

// epos[e] = CSR slot of edge e; esd[2*pos..] = (src, dst)
__global__ void k_fill(const int* __restrict__ ei, const int* __restrict__ rps,
                       int* __restrict__ cur_s, int* __restrict__ epos,
                       int* __restrict__ esd) {
  int e = blockIdx.x * 256 + threadIdx.x;
  if (e >= EE) return;
  int s = ei[e], d = ei[EE + e];
  int ps = atomicAdd(&cur_s[s], 1);
  int pos = rps[s] + ps;
  epos[e] = pos;
  esd[2 * pos] = s;
  esd[2 * pos + 1] = d;
}

// graph segment offsets from sorted batch
__global__ void k_goff(const int* __restrict__ batch, int* __restrict__ goff) {
  int g = blockIdx.x * 256 + threadIdx.x;
  if (g > BB) return;
  int lo = 0, hi = NN;
  while (lo < hi) {
    int mid = (lo + hi) >> 1;
    if (batch[mid] < g) lo = mid + 1; else hi = mid;
  }
  goff[g] = lo;
}

// ---------------- fused NNConv message kernel (MFMA) ----------------
// Block: NPB=10 src nodes, 4 waves, K in 4 chunks of 32 (16 bf16-pairs).
// Phase 1: G chunk via mfma_f32_16x16x32_bf16 -> LDS layout [m][kpq][f][4] (kp quartet
//   innermost -> b128 LDS writes/reads). Wave w owns kp quartet w.
// Phase 2: edges in CSR order (induction-derived addresses); per edge-chunk:
//   4x ds_read_b128 (G) + 4x uniform uint4 (hn1s) + 16 dot2 + 1 atomicAdd.
__global__ __launch_bounds__(256, 4) void k_conv(
    const uint_t* __restrict__ hpk, const uint_t* __restrict__ hn1s,
    const uint_t* __restrict__ Wn2m, const float* __restrict__ nbias,
    const int* __restrict__ rps, const int* __restrict__ esd,
    float* __restrict__ aggr) {
  __shared__ uint_t Gp[NPB * 4 * 64 * 4];  // 40 KB
  const int tid = threadIdx.x;
  const int w = tid >> 6, lane = tid & 63;
  const int q = lane >> 4, n16 = lane & 15;
  const int n0 = blockIdx.x * NPB;

  FragU a0, a1;
  {
    int nn = n0 + n16;
    if (nn > NN - 1) nn = NN - 1;
    const uint4* ap = (const uint4*)(hpk + (size_t)nn * 32);
    a0.u = ap[q];
    a1.u = ap[4 + q];
  }
  const int e0 = rps[n0], e1 = rps[n0 + NPB];

  for (int c = 0; c < 4; ++c) {
    if (c) __syncthreads();
    // ---- phase 1: wave w computes kp quartet (global pairs c*16 + w*4 + kk) ----
    for (int fc = 0; fc < 4; ++fc) {
      uint_t pk[4][4];  // [kk][r]
#pragma unroll
      for (int kk = 0; kk < 4; ++kk) {
        const int kpg = c * 16 + w * 4 + kk;
        const uint4* bp = (const uint4*)Wn2m + (size_t)(kpg * 4 + fc) * 256 + lane;
        FragU b00, b01, b10, b11;
        b00.u = bp[0];    // par0 hf0
        b01.u = bp[64];   // par0 hf1
        b10.u = bp[128];  // par1 hf0
        b11.u = bp[192];  // par1 hf1
        f32x4_t acc0 = {0.f, 0.f, 0.f, 0.f};
        f32x4_t acc1 = {0.f, 0.f, 0.f, 0.f};
        acc0 = __builtin_amdgcn_mfma_f32_16x16x32_bf16(a0.b, b00.b, acc0, 0, 0, 0);
        acc0 = __builtin_amdgcn_mfma_f32_16x16x32_bf16(a1.b, b01.b, acc0, 0, 0, 0);
        acc1 = __builtin_amdgcn_mfma_f32_16x16x32_bf16(a0.b, b10.b, acc1, 0, 0, 0);
        acc1 = __builtin_amdgcn_mfma_f32_16x16x32_bf16(a1.b, b11.b, acc1, 0, 0, 0);
#pragma unroll
        for (int r = 0; r < 4; ++r)
          pk[kk][r] = pack2(acc0[r], acc1[r]);
      }
#pragma unroll
      for (int r = 0; r < 4; ++r) {
        const int m = q * 4 + r;  // D row = node index
        if (m < NPB) {
          uint4 v;
          v.x = pk[0][r]; v.y = pk[1][r]; v.z = pk[2][r]; v.w = pk[3][r];
          ((uint4*)Gp)[(m * 4 + w) * 64 + fc * 16 + n16] = v;
        }
      }
    }
    __syncthreads();
    // ---- phase 2 ----
    for (int ii = e0 + w; ii < e1; ii += 4) {
      const int iiu = __builtin_amdgcn_readfirstlane(ii);
      const int src = __builtin_amdgcn_readfirstlane(esd[2 * iiu]);
      const int dst = __builtin_amdgcn_readfirstlane(esd[2 * iiu + 1]);
      const int m = src - n0;
      float p = (c == 0) ? nbias[(size_t)src * 64 + lane] : 0.f;
      const uint4* hp = (const uint4*)(hn1s + (size_t)iiu * 64 + c * 16);
      const uint4* gb = (const uint4*)Gp + (size_t)m * 256 + lane;
#pragma unroll
      for (int kpq = 0; kpq < 4; ++kpq) {
        uint4 gv = gb[kpq * 64];
        uint4 hv = hp[kpq];
        p = dot2a(gv.x, hv.x, p);
        p = dot2a(gv.y, hv.y, p);
        p = dot2a(gv.z, hv.z, p);
        p = dot2a(gv.w, hv.w, p);
      }
      atomicAdd(&aggr[(size_t)dst * 64 + lane], p);
    }
  }
}

// ---------------- h update: residual + aggr + root GEMM; re-zeros aggr ----------------
__global__ void k_update(float* __restrict__ h, uint_t* __restrict__ hpk,
                         float* __restrict__ aggr, const float* __restrict__ bn2,
                         const float* __restrict__ root, const float* __restrict__ cb,
                         float* __restrict__ nbias, int l) {
  __shared__ float hl[DD];
  const int n = blockIdx.x, f = threadIdx.x;
  hl[f] = h[(size_t)n * DD + f];
  __syncthreads();
  float acc = hl[f] + aggr[(size_t)n * DD + f] + cb[l * DD + f];
  aggr[(size_t)n * DD + f] = 0.f;  // re-zero for next layer
  const float* rp = root + (size_t)l * DD2 + f;
#pragma unroll
  for (int d = 0; d < DD; ++d) acc += hl[d] * rp[d * DD];
  h[(size_t)n * DD + f] = acc;
  float other = __shfl_down(acc, 1);
  if ((f & 1) == 0)
    hpk[(size_t)n * 32 + (f >> 1)] = pack2(acc, other);
  __syncthreads();
  hl[f] = acc;
  __syncthreads();
  float nb = 0.f;
#pragma unroll
  for (int d = 0; d < DD; ++d) nb += hl[d] * bn2[d * DD + f];
  nbias[(size_t)n * DD + f] = nb;
}

// ---------------- fused Set2Set (3x LSTM+attention) + output MLP ----------------
#define EVCAP 2048
__global__ void k_s2s(const float* __restrict__ h, const int* __restrict__ goff,
                      const float* __restrict__ Wiht, const float* __restrict__ Whht,
                      const float* __restrict__ lb,
                      const float* __restrict__ Wo1, const float* __restrict__ bo1,
                      const float* __restrict__ Wo2, const float* __restrict__ bo2,
                      void* __restrict__ outv, const int* __restrict__ flag) {
  __shared__ float qsl[K1];
  __shared__ float hsl[DD];
  __shared__ float csl[DD];
  __shared__ float gl[4][DD];
  __shared__ float red[256];
  __shared__ float ev[EVCAP];
  __shared__ float rp4[4][DD];
  const int g = blockIdx.x, tid = threadIdx.x;

  if (tid < K1) qsl[tid] = 0.f;
  else if (tid < K1 + DD) hsl[tid - K1] = 0.f;
  else csl[tid - K1 - DD] = 0.f;
  __syncthreads();

  const int i0 = goff[g];
  int cnt = goff[g + 1] - i0;
  if (cnt > EVCAP) cnt = EVCAP;

  for (int m = 0; m < MM; ++m) {
    // ---- LSTM: thread tid computes gate column j = tid (coalesced weights) ----
    {
      float a = lb[tid];
      for (int i = 0; i < K1; ++i) a += qsl[i] * Wiht[i * 256 + tid];
      for (int i = 0; i < DD; ++i) a += hsl[i] * Whht[i * 256 + tid];
      gl[tid >> 6][tid & 63] = a;
    }
    __syncthreads();
    if (tid < DD) {
      float ig = sigmf_(gl[0][tid]), fg = sigmf_(gl[1][tid]);
      float gg = tanhf(gl[2][tid]), og = sigmf_(gl[3][tid]);
      float c = fg * csl[tid] + ig * gg;
      csl[tid] = c;
      hsl[tid] = og * tanhf(c);
    }
    __syncthreads();
    // ---- attention, q = hsl ----
    float lmax = -1e30f;
    for (int jj = tid; jj < cnt; jj += 256) {
      const float* hp = h + (size_t)(i0 + jj) * DD;
      float e = 0.f;
#pragma unroll
      for (int d = 0; d < DD; ++d) e += hp[d] * hsl[d];
      ev[jj] = e;
      lmax = fmaxf(lmax, e);
    }
    red[tid] = lmax;
    __syncthreads();
    for (int s = 128; s > 0; s >>= 1) {
      if (tid < s) red[tid] = fmaxf(red[tid], red[tid + s]);
      __syncthreads();
    }
    const float emax = red[0];
    __syncthreads();
    float lsum = 0.f;
    for (int jj = tid; jj < cnt; jj += 256) {
      float ex = expf(ev[jj] - emax);
      ev[jj] = ex;
      lsum += ex;
    }
    red[tid] = lsum;
    __syncthreads();
    for (int s = 128; s > 0; s >>= 1) {
      if (tid < s) red[tid] += red[tid + s];
      __syncthreads();
    }
    const float denom = red[0];
    const int f = tid & 63, grp = tid >> 6;
    float acc = 0.f;
    for (int jj = grp; jj < cnt; jj += 4)
      acc += ev[jj] * h[(size_t)(i0 + jj) * DD + f];
    rp4[grp][f] = acc;
    __syncthreads();
    if (tid < DD) {
      float r = rp4[0][tid] + rp4[1][tid] + rp4[2][tid] + rp4[3][tid];
      r = (cnt > 0 && denom > 0.f) ? r / denom : 0.f;
      qsl[tid] = hsl[tid];
      qsl[DD + tid] = r;
    }
    __syncthreads();
  }
  // ---- output MLP (first wave) ----
  if (tid < DD) {
    float t = bo1[tid];
    for (int i = 0; i < K1; ++i) t += qsl[i] * Wo1[i * DD + tid];
    float s = siluf_(t) * Wo2[tid];
    for (int off = 32; off > 0; off >>= 1) s += __shfl_down(s, off);
    if (tid == 0) {
      float v = s + bo2[0];
      if (*flag) ((ushort_t*)outv)[g] = f2bf(v);
      else       ((float*)outv)[g] = v;
    }
  }
}

extern "C" void kernel_launch(void* const* d_in, const int* in_sizes, int n_in,
                              void* d_out, int out_size, void* d_ws, size_t ws_size,
                              hipStream_t stream) {
  const void* x_r    = d_in[0];
  const int*  ei     = (const int*)d_in[1];
  const void* ea_r   = d_in[2];
  const int*  batch  = (const int*)d_in[3];
  const void* W0_r   = d_in[4];
  const void* b0_r   = d_in[5];
  const void* Wn1_r  = d_in[6];
  const void* bn1_r  = d_in[7];
  const void* Wn2_r  = d_in[8];
  const void* bn2_r  = d_in[9];
  const void* root_r = d_in[10];
  const void* cb_r   = d_in[11];
  const void* Wih_r  = d_in[12];
  const void* Whh_r  = d_in[13];
  const void* lb_r   = d_in[14];
  const void* Wo1_r  = d_in[15];
  const void* bo1_r  = d_in[16];
  const void* Wo2_r  = d_in[17];
  const void* bo2_r  = d_in[18];

  char* w = (char*)d_ws;
  size_t off = 0;
  auto alloc = [&](size_t bytes) -> void* {
    void* p = w + off;
    off = (off + bytes + 255) & ~(size_t)255;
    return p;
  };
  int* flag = (int*)alloc(4);
  float* xc    = (float*)alloc((size_t)NN * DIN_ * 4);
  float* eac   = (float*)alloc((size_t)EE * 4 * 4);
  float* W0c   = (float*)alloc((size_t)DIN_ * DD * 4);
  float* b0c   = (float*)alloc((size_t)DD * 4);
  float* Wn1c  = (float*)alloc((size_t)4 * K1 * 4);
  float* bn1c  = (float*)alloc((size_t)K1 * 4);
  float* bn2c  = (float*)alloc((size_t)DD2 * 4);
  float* rootc = (float*)alloc((size_t)LL * DD2 * 4);
  float* cbc   = (float*)alloc((size_t)LL * DD * 4);
  float* Wihc  = (float*)alloc((size_t)4 * DD * K1 * 4);
  float* Whhc  = (float*)alloc((size_t)4 * DD * DD * 4);
  float* lbc   = (float*)alloc((size_t)4 * DD * 4);
  float* Wo1c  = (float*)alloc((size_t)K1 * DD * 4);
  float* bo1c  = (float*)alloc((size_t)DD * 4);
  float* Wo2c  = (float*)alloc((size_t)DD * 4);
  float* bo2c  = (float*)alloc((size_t)4);
  float* Wiht  = (float*)alloc((size_t)K1 * 256 * 4);          // 128 KB
  float* Whht  = (float*)alloc((size_t)DD * 256 * 4);          // 64 KB
  uint_t* Wn2m = (uint_t*)alloc((size_t)64 * 4 * 2 * 2 * 64 * 4 * 4);  // 1 MB
  float*  h    = (float*)alloc((size_t)NN * DD * 4);           // 2.56 MB
  uint_t* hpk  = (uint_t*)alloc((size_t)NN * 32 * 4);          // 1.28 MB
  uint_t* hn1s = (uint_t*)alloc((size_t)EE * (K1 / 2) * 4);    // 10.24 MB (CSR order)
  float*  aggr = (float*)alloc((size_t)NN * DD * 4);           // 2.56 MB
  float*  nbias= (float*)alloc((size_t)NN * DD * 4);           // 2.56 MB
  int* cnts  = (int*)alloc((size_t)2 * NN * 4);
  int* rps   = (int*)alloc((size_t)(NN + 1) * 4);
  int* epos  = (int*)alloc((size_t)EE * 4);
  int* esd   = (int*)alloc((size_t)2 * EE * 4);
  int* goff  = (int*)alloc((size_t)(BB + 1) * 4);

  int* cnt_s = cnts;
  int* cur_s = cnts + NN;

  hipMemsetAsync(cnts, 0, (size_t)2 * NN * 4, stream);
  hipMemsetAsync(aggr, 0, (size_t)NN * DD * 4, stream);

  k_detect<<<1, 256, 0, stream>>>((const ushort_t*)ea_r, flag);

  CanonArgs ca;
  const void* srcs[NCANON] = {x_r, ea_r, W0_r, b0_r, Wn1_r, bn1_r, bn2_r, root_r,
                              cb_r, Wih_r, Whh_r, lb_r, Wo1_r, bo1_r, Wo2_r, bo2_r};
  float* dsts[NCANON] = {xc, eac, W0c, b0c, Wn1c, bn1c, bn2c, rootc,
                         cbc, Wihc, Whhc, lbc, Wo1c, bo1c, Wo2c, bo2c};
  int cnts_c[NCANON] = {NN * DIN_, EE * 4, DIN_ * DD, DD, 4 * K1, K1, DD2, LL * DD2,
                        LL * DD, 4 * DD * K1, 4 * DD * DD, 4 * DD, K1 * DD, DD, DD, 1};
  for (int i = 0; i < NCANON; ++i) { ca.src[i] = srcs[i]; ca.dst[i] = dsts[i]; ca.n[i] = cnts_c[i]; }
  {
    dim3 grid((EE * 4 + 255) / 256, NCANON);
    k_canon<<<grid, 256, 0, stream>>>(ca, flag);
  }
  k_wn2m<<<1024, 256, 0, stream>>>(Wn2_r, Wn2m, flag);
  k_wT<<<(4 * DD * K1 + 255) / 256, 256, 0, stream>>>(Wihc, Whhc, Wiht, Whht);

  k_embed<<<NN, DD, 0, stream>>>(xc, W0c, b0c, bn2c, h, hpk, nbias);
  k_hist<<<(EE + 255) / 256, 256, 0, stream>>>(ei, cnt_s);
  k_scan<<<1, 1024, 0, stream>>>(cnt_s, rps);
  k_fill<<<(EE + 255) / 256, 256, 0, stream>>>(ei, rps, cur_s, epos, esd);
  k_goff<<<(BB + 1 + 255) / 256, 256, 0, stream>>>(batch, goff);
  k_edgemlp<<<(EE * (K1 / 2) + 255) / 256, 256, 0, stream>>>(eac, Wn1c, bn1c, epos, hn1s);

  for (int l = 0; l < LL; ++l) {
    k_conv<<<NN / NPB, 256, 0, stream>>>(hpk, hn1s, Wn2m, nbias, rps, esd, aggr);
    k_update<<<NN, DD, 0, stream>>>(h, hpk, aggr, bn2c, rootc, cbc, nbias, l);
  }

  k_s2s<<<BB, 256, 0, stream>>>(h, goff, Wiht, Whht, lbc, Wo1c, bo1c, Wo2c, bo2c,
                                d_out, flag);
}